// Round 1
// baseline (1960.690 us; speedup 1.0000x reference)
//
#include <hip/hip_runtime.h>
#include <hip/hip_bf16.h>

#define S_LEN 1024
#define HID 2048
#define NHEADS 16
#define KVHEADS 4
#define HD 128
#define KVW (KVHEADS * HD)      // 512
#define FETCH_MAX 204
#define ALPHA_C 5.0f
#define SCALE_C 0.08838834764831845f

// ---------------- generic fp32 GEMM: C[M][N] = A[M][K] @ B[N][K]^T ----------
__global__ __launch_bounds__(256) void gemm_nt64(
    const float* __restrict__ A, const float* __restrict__ B,
    float* __restrict__ C, int M, int N, int K) {
  __shared__ float As[16][65];
  __shared__ float Bs[16][65];
  const int tid = threadIdx.x;
  const int tx = tid & 15, ty = tid >> 4;
  const int bm = blockIdx.y * 64, bn = blockIdx.x * 64;
  const int r = tid >> 2, c4 = (tid & 3) << 2;
  float acc[4][4] = {{0.f}};
  for (int k0 = 0; k0 < K; k0 += 16) {
    float4 av = *(const float4*)(A + (size_t)(bm + r) * K + (k0 + c4));
    float4 bv = *(const float4*)(B + (size_t)(bn + r) * K + (k0 + c4));
    As[c4 + 0][r] = av.x; As[c4 + 1][r] = av.y; As[c4 + 2][r] = av.z; As[c4 + 3][r] = av.w;
    Bs[c4 + 0][r] = bv.x; Bs[c4 + 1][r] = bv.y; Bs[c4 + 2][r] = bv.z; Bs[c4 + 3][r] = bv.w;
    __syncthreads();
#pragma unroll
    for (int kk = 0; kk < 16; ++kk) {
      float a0 = As[kk][ty * 4 + 0], a1 = As[kk][ty * 4 + 1],
            a2 = As[kk][ty * 4 + 2], a3 = As[kk][ty * 4 + 3];
      float b0 = Bs[kk][tx * 4 + 0], b1 = Bs[kk][tx * 4 + 1],
            b2 = Bs[kk][tx * 4 + 2], b3 = Bs[kk][tx * 4 + 3];
      acc[0][0] += a0 * b0; acc[0][1] += a0 * b1; acc[0][2] += a0 * b2; acc[0][3] += a0 * b3;
      acc[1][0] += a1 * b0; acc[1][1] += a1 * b1; acc[1][2] += a1 * b2; acc[1][3] += a1 * b3;
      acc[2][0] += a2 * b0; acc[2][1] += a2 * b1; acc[2][2] += a2 * b2; acc[2][3] += a2 * b3;
      acc[3][0] += a3 * b0; acc[3][1] += a3 * b1; acc[3][2] += a3 * b2; acc[3][3] += a3 * b3;
    }
    __syncthreads();
  }
#pragma unroll
  for (int i = 0; i < 4; ++i)
#pragma unroll
    for (int j = 0; j < 4; ++j)
      C[(size_t)(bm + ty * 4 + i) * N + (bn + tx * 4 + j)] = acc[i][j];
}

// ---------------- RoPE in place on [S][nh*HD] -------------------------------
__global__ __launch_bounds__(256) void rope_kernel(
    float* __restrict__ X, const float* __restrict__ cosb,
    const float* __restrict__ sinb, int nh) {
  int idx = blockIdx.x * 256 + threadIdx.x;
  int total = S_LEN * nh * 64;
  if (idx >= total) return;
  int d = idx & 63;
  int h = (idx >> 6) % nh;
  int s = idx / (nh * 64);
  float* xp = X + (size_t)s * (nh * HD) + h * HD;
  float x1 = xp[d], x2 = xp[d + 64];
  float c1 = cosb[s * HD + d],      s1 = sinb[s * HD + d];
  float c2 = cosb[s * HD + d + 64], s2 = sinb[s * HD + d + 64];
  xp[d]      = x1 * c1 - x2 * s1;
  xp[d + 64] = x2 * c2 + x1 * s2;
}

// ---------------- spec[h][t][j] = SCALE * Qs_h[t]·K_{h/4}[j] ----------------
__global__ __launch_bounds__(256) void spec_gemm(
    const float* __restrict__ Qs, const float* __restrict__ Kmat,
    float* __restrict__ spec) {
  const int h = blockIdx.z;
  const float* A = Qs + h * HD;            // [S][HID]
  const float* B = Kmat + (h >> 2) * HD;   // [S][KVW]
  float* C = spec + (size_t)h * S_LEN * S_LEN;
  __shared__ float As[16][65];
  __shared__ float Bs[16][65];
  const int tid = threadIdx.x;
  const int tx = tid & 15, ty = tid >> 4;
  const int bm = blockIdx.y * 64, bn = blockIdx.x * 64;
  const int r = tid >> 2, c4 = (tid & 3) << 2;
  float acc[4][4] = {{0.f}};
  for (int k0 = 0; k0 < HD; k0 += 16) {
    float4 av = *(const float4*)(A + (size_t)(bm + r) * HID + (k0 + c4));
    float4 bv = *(const float4*)(B + (size_t)(bn + r) * KVW + (k0 + c4));
    As[c4 + 0][r] = av.x; As[c4 + 1][r] = av.y; As[c4 + 2][r] = av.z; As[c4 + 3][r] = av.w;
    Bs[c4 + 0][r] = bv.x; Bs[c4 + 1][r] = bv.y; Bs[c4 + 2][r] = bv.z; Bs[c4 + 3][r] = bv.w;
    __syncthreads();
#pragma unroll
    for (int kk = 0; kk < 16; ++kk) {
      float a0 = As[kk][ty * 4 + 0], a1 = As[kk][ty * 4 + 1],
            a2 = As[kk][ty * 4 + 2], a3 = As[kk][ty * 4 + 3];
      float b0 = Bs[kk][tx * 4 + 0], b1 = Bs[kk][tx * 4 + 1],
            b2 = Bs[kk][tx * 4 + 2], b3 = Bs[kk][tx * 4 + 3];
      acc[0][0] += a0 * b0; acc[0][1] += a0 * b1; acc[0][2] += a0 * b2; acc[0][3] += a0 * b3;
      acc[1][0] += a1 * b0; acc[1][1] += a1 * b1; acc[1][2] += a1 * b2; acc[1][3] += a1 * b3;
      acc[2][0] += a2 * b0; acc[2][1] += a2 * b1; acc[2][2] += a2 * b2; acc[2][3] += a2 * b3;
      acc[3][0] += a3 * b0; acc[3][1] += a3 * b1; acc[3][2] += a3 * b2; acc[3][3] += a3 * b3;
    }
    __syncthreads();
  }
#pragma unroll
  for (int i = 0; i < 4; ++i)
#pragma unroll
    for (int j = 0; j < 4; ++j)
      C[(size_t)(bm + ty * 4 + i) * S_LEN + (bn + tx * 4 + j)] = acc[i][j] * SCALE_C;
}

// ---------------- per-(h,t): rowmax + count(>= max-ALPHA) -------------------
__global__ __launch_bounds__(256) void count_kernel(
    const float* __restrict__ spec, int* __restrict__ cnt) {
  const int t = blockIdx.x, h = blockIdx.y, tid = threadIdx.x;
  __shared__ float redf[256];
  __shared__ int redi[256];
  const float* row = spec + ((size_t)h * S_LEN + t) * S_LEN;
  float mx = -1e30f;
  for (int j = tid; j <= t; j += 256) mx = fmaxf(mx, row[j]);
  redf[tid] = mx; __syncthreads();
  for (int s = 128; s; s >>= 1) { if (tid < s) redf[tid] = fmaxf(redf[tid], redf[tid + s]); __syncthreads(); }
  const float cut = redf[0] - ALPHA_C;
  int c = 0;
  for (int j = tid; j <= t; j += 256) c += (row[j] >= cut) ? 1 : 0;
  redi[tid] = c; __syncthreads();
  for (int s = 128; s; s >>= 1) { if (tid < s) redi[tid] += redi[tid + s]; __syncthreads(); }
  if (tid == 0) cnt[h * S_LEN + t] = redi[0];
}

// fn[t] = min( floor(mean_h cnt), FETCH_MAX )  (mean/16 + int cast == >>4)
__global__ __launch_bounds__(256) void fn_kernel(
    const int* __restrict__ cnt, int* __restrict__ fn) {
  int t = blockIdx.x * 256 + threadIdx.x;
  if (t >= S_LEN) return;
  int s = 0;
#pragma unroll
  for (int h = 0; h < NHEADS; ++h) s += cnt[h * S_LEN + t];
  int f = s >> 4;
  fn[t] = f > FETCH_MAX ? FETCH_MAX : f;
}

// ---------------- exact k-th largest per (h,t) via radix select -------------
__global__ __launch_bounds__(256) void thr_kernel(
    const float* __restrict__ spec, const int* __restrict__ fn,
    float* __restrict__ thr) {
  const int t = blockIdx.x, h = blockIdx.y;
  if (t < FETCH_MAX) return;
  const int tid = threadIdx.x;
  __shared__ int hist[256];
  __shared__ unsigned pref_s;
  __shared__ int k_s;
  const float* row = spec + ((size_t)h * S_LEN + t) * S_LEN;
  int k = fn[t];            // >= 1, <= 204 <= t+1
  unsigned prefix = 0;
  for (int r = 3; r >= 0; --r) {
    hist[tid] = 0;
    __syncthreads();
    const int shift = r * 8;
    for (int j = tid; j <= t; j += 256) {
      unsigned bits = __float_as_uint(row[j]);
      unsigned u = (bits & 0x80000000u) ? ~bits : (bits | 0x80000000u);
      bool cand = (r == 3) || ((u >> (shift + 8)) == (prefix >> (shift + 8)));
      if (cand) atomicAdd(&hist[(u >> shift) & 255], 1);
    }
    __syncthreads();
    if (tid == 0) {
      int cum = 0, b = 255;
      for (; b >= 0; --b) { cum += hist[b]; if (cum >= k) break; }
      k_s = k - (cum - hist[b]);
      pref_s = prefix | ((unsigned)b << shift);
    }
    __syncthreads();
    prefix = pref_s; k = k_s;
    __syncthreads();
  }
  if (tid == 0) {
    unsigned u = prefix;
    unsigned bits = (u & 0x80000000u) ? (u & 0x7fffffffu) : ~u;
    thr[h * S_LEN + t] = __uint_as_float(bits);
  }
}

// ---------------- masked attention, one block per (h, t) --------------------
__global__ __launch_bounds__(256) void attn_kernel(
    const float* __restrict__ Q, const float* __restrict__ Kmat,
    const float* __restrict__ V, const float* __restrict__ spec,
    const float* __restrict__ thr, float* __restrict__ out) {
  const int t = blockIdx.x, h = blockIdx.y, tid = threadIdx.x;
  __shared__ float qrow[HD];
  __shared__ float p[S_LEN];
  __shared__ float red[256];
  const float* qp = Q + (size_t)t * HID + h * HD;
  if (tid < HD) qrow[tid] = qp[tid];
  __syncthreads();
  const float* Kh = Kmat + (h >> 2) * HD;
  const float* specrow = spec + ((size_t)h * S_LEN + t) * S_LEN;
  const float thrv = (t >= FETCH_MAX) ? thr[h * S_LEN + t] : 0.f;
  const bool full = (t < FETCH_MAX);
  float lmax = -1e30f;
  for (int j = tid; j <= t; j += 256) {
    float sc = -1e30f;
    if (full || specrow[j] >= thrv) {
      const float* kr = Kh + (size_t)j * KVW;
      float dot = 0.f;
#pragma unroll
      for (int d = 0; d < HD; d += 4) {
        float4 kv = *(const float4*)(kr + d);
        dot += qrow[d] * kv.x + qrow[d + 1] * kv.y + qrow[d + 2] * kv.z + qrow[d + 3] * kv.w;
      }
      sc = dot * SCALE_C;
    }
    p[j] = sc;
    lmax = fmaxf(lmax, sc);
  }
  red[tid] = lmax; __syncthreads();
  for (int s = 128; s; s >>= 1) { if (tid < s) red[tid] = fmaxf(red[tid], red[tid + s]); __syncthreads(); }
  const float m = red[0];
  __syncthreads();
  float lsum = 0.f;
  for (int j = tid; j <= t; j += 256) {
    float e = expf(p[j] - m);   // masked (-1e30) underflows to exactly 0
    p[j] = e;
    lsum += e;
  }
  red[tid] = lsum; __syncthreads();
  for (int s = 128; s; s >>= 1) { if (tid < s) red[tid] += red[tid + s]; __syncthreads(); }
  const float inv = 1.0f / red[0];
  __syncthreads();
  // PV: threads split into two halves over j, each owns one d
  const float* Vh = V + (h >> 2) * HD;
  const int half = tid >> 7;       // 0/1
  const int d = tid & 127;
  float accv = 0.f;
  for (int j = half; j <= t; j += 2) {
    float pj = p[j];
    if (pj != 0.f) accv += pj * Vh[(size_t)j * KVW + d];
  }
  red[tid] = accv; __syncthreads();
  if (tid < HD) {
    out[(size_t)t * HID + h * HD + d] = (red[tid] + red[tid + 128]) * inv;
  }
}

extern "C" void kernel_launch(void* const* d_in, const int* in_sizes, int n_in,
                              void* d_out, int out_size, void* d_ws, size_t ws_size,
                              hipStream_t stream) {
  const float* hidden = (const float*)d_in[0];
  const float* prev   = (const float*)d_in[1];
  const float* cosb   = (const float*)d_in[2];
  const float* sinb   = (const float*)d_in[3];
  const float* Wq     = (const float*)d_in[4];
  const float* Wk     = (const float*)d_in[5];
  const float* Wv     = (const float*)d_in[6];
  const float* Wo     = (const float*)d_in[7];
  float* out = (float*)d_out;

  char* ws = (char*)d_ws;
  float* Q    = (float*)(ws + 0);
  float* Qs   = (float*)(ws + (8u << 20));
  float* Kb   = (float*)(ws + (16u << 20));
  float* Vb   = (float*)(ws + (18u << 20));
  float* AO   = (float*)(ws + (20u << 20));
  float* spec = (float*)(ws + (28u << 20));
  int*   cnt  = (int*)  (ws + (92u << 20));
  int*   fn   = (int*)  (ws + (92u << 20) + (64u << 10));
  float* thr  = (float*)(ws + (92u << 20) + (80u << 10));

  // projections
  gemm_nt64<<<dim3(HID / 64, S_LEN / 64), 256, 0, stream>>>(hidden, Wq, Q,  S_LEN, HID, HID);
  gemm_nt64<<<dim3(HID / 64, S_LEN / 64), 256, 0, stream>>>(prev,   Wq, Qs, S_LEN, HID, HID);
  gemm_nt64<<<dim3(KVW / 64, S_LEN / 64), 256, 0, stream>>>(hidden, Wk, Kb, S_LEN, KVW, HID);
  gemm_nt64<<<dim3(KVW / 64, S_LEN / 64), 256, 0, stream>>>(hidden, Wv, Vb, S_LEN, KVW, HID);
  // RoPE
  rope_kernel<<<(S_LEN * NHEADS * 64 + 255) / 256, 256, 0, stream>>>(Q,  cosb, sinb, NHEADS);
  rope_kernel<<<(S_LEN * NHEADS * 64 + 255) / 256, 256, 0, stream>>>(Qs, cosb, sinb, NHEADS);
  rope_kernel<<<(S_LEN * KVHEADS * 64 + 255) / 256, 256, 0, stream>>>(Kb, cosb, sinb, KVHEADS);
  // speculative scores
  spec_gemm<<<dim3(S_LEN / 64, S_LEN / 64, NHEADS), 256, 0, stream>>>(Qs, Kb, spec);
  // mask statistics
  count_kernel<<<dim3(S_LEN, NHEADS), 256, 0, stream>>>(spec, cnt);
  fn_kernel<<<S_LEN / 256, 256, 0, stream>>>(cnt, fn);
  thr_kernel<<<dim3(S_LEN, NHEADS), 256, 0, stream>>>(spec, fn, thr);
  // attention
  attn_kernel<<<dim3(S_LEN, NHEADS), 256, 0, stream>>>(Q, Kb, Vb, spec, thr, AO);
  // output projection
  gemm_nt64<<<dim3(HID / 64, S_LEN / 64), 256, 0, stream>>>(AO, Wo, out, S_LEN, HID, HID);
}

// Round 3
// 626.913 us; speedup vs baseline: 3.1275x; 3.1275x over previous
//
#include <hip/hip_runtime.h>
#include <hip/hip_bf16.h>

#define S_LEN 1024
#define HID 2048
#define NHEADS 16
#define KVHEADS 4
#define HD 128
#define KVW 512
#define FETCH_MAX 204
#define ALPHA_C 5.0f
#define SCALE_C 0.08838834764831845f

typedef __attribute__((ext_vector_type(8))) short bf16x8;
typedef __attribute__((ext_vector_type(4))) float f32x4;
typedef unsigned short ushort_t;

#define MFMA16(a, b, c) __builtin_amdgcn_mfma_f32_16x16x32_bf16(a, b, c, 0, 0, 0)

__device__ __forceinline__ ushort_t f2bf(float f) {
  unsigned u = __float_as_uint(f);
  return (ushort_t)((u + 0x7fffu + ((u >> 16) & 1u)) >> 16);
}
__device__ __forceinline__ float bf2f(ushort_t h) {
  return __uint_as_float(((unsigned)h) << 16);
}

// ---------------- fp32 -> bf16, 8 elems/thread ------------------------------
__global__ __launch_bounds__(256) void to_bf16(const float* __restrict__ in,
                                               ushort_t* __restrict__ out, int n) {
  int i = (blockIdx.x * 256 + threadIdx.x) * 8;
  if (i >= n) return;
  float4 a = *(const float4*)(in + i);
  float4 b = *(const float4*)(in + i + 4);
  bf16x8 v;
  v[0] = (short)f2bf(a.x); v[1] = (short)f2bf(a.y);
  v[2] = (short)f2bf(a.z); v[3] = (short)f2bf(a.w);
  v[4] = (short)f2bf(b.x); v[5] = (short)f2bf(b.y);
  v[6] = (short)f2bf(b.z); v[7] = (short)f2bf(b.w);
  *(bf16x8*)(out + i) = v;
}

// ---------------- fp32 -> bf16 hi/lo split, 8 elems/thread ------------------
__global__ __launch_bounds__(256) void to_bf16_split(const float* __restrict__ in,
                                                     ushort_t* __restrict__ hi,
                                                     ushort_t* __restrict__ lo, int n) {
  int i = (blockIdx.x * 256 + threadIdx.x) * 8;
  if (i >= n) return;
  bf16x8 vh, vl;
#pragma unroll
  for (int q = 0; q < 8; ++q) {
    float x = in[i + q];
    ushort_t h = f2bf(x);
    vh[q] = (short)h;
    vl[q] = (short)f2bf(x - bf2f(h));
  }
  *(bf16x8*)(hi + i) = vh;
  *(bf16x8*)(lo + i) = vl;
}

// ---------------- 1-pass projection GEMM + optional RoPE, bf16 out ----------
__global__ __launch_bounds__(256) void proj_gemm(
    const ushort_t* __restrict__ A, const ushort_t* __restrict__ W,
    ushort_t* __restrict__ Out, const float* __restrict__ cosb,
    const float* __restrict__ sinb, int N, int do_rope) {
  __shared__ char sm[32768];
  char* As = sm;
  char* Bs = sm + 16384;
  const int tid = threadIdx.x, w = tid >> 6, lane = tid & 63;
  const int lo = lane & 15, hi = lane >> 4;
  const int bm = blockIdx.y * 128, bn = blockIdx.x * 128;
  f32x4 acc[2][8];
#pragma unroll
  for (int m = 0; m < 2; ++m)
#pragma unroll
    for (int n = 0; n < 8; ++n) acc[m][n] = f32x4{0.f, 0.f, 0.f, 0.f};

  for (int k0 = 0; k0 < HID; k0 += 64) {
#pragma unroll
    for (int p = 0; p < 4; ++p) {
      int idx = p * 256 + tid;
      int r = idx >> 3, c = idx & 7;
      bf16x8 va = *(const bf16x8*)(A + (size_t)(bm + r) * HID + k0 + c * 8);
      *(bf16x8*)(As + ((r * 128 + c * 16) ^ ((r & 7) << 4))) = va;
      bf16x8 vb = *(const bf16x8*)(W + (size_t)(bn + r) * HID + k0 + c * 8);
      *(bf16x8*)(Bs + ((r * 128 + c * 16) ^ ((r & 7) << 4))) = vb;
    }
    __syncthreads();
#pragma unroll
    for (int ks = 0; ks < 2; ++ks) {
      const int ko = ks * 64 + hi * 16;
      bf16x8 af[2], bfr[8];
#pragma unroll
      for (int m = 0; m < 2; ++m) {
        int r = w * 32 + m * 16 + lo;
        af[m] = *(const bf16x8*)(As + ((r * 128 + ko) ^ ((r & 7) << 4)));
      }
#pragma unroll
      for (int n = 0; n < 8; ++n) {
        int r = n * 16 + lo;
        bfr[n] = *(const bf16x8*)(Bs + ((r * 128 + ko) ^ ((r & 7) << 4)));
      }
#pragma unroll
      for (int m = 0; m < 2; ++m)
#pragma unroll
        for (int n = 0; n < 8; ++n) acc[m][n] = MFMA16(af[m], bfr[n], acc[m][n]);
    }
    __syncthreads();
  }
#pragma unroll
  for (int m = 0; m < 2; ++m)
#pragma unroll
    for (int nf = 0; nf < 4; ++nf)
#pragma unroll
      for (int r = 0; r < 4; ++r) {
        int t = bm + w * 32 + m * 16 + hi * 4 + r;
        int d = nf * 16 + lo;
        float x1 = acc[m][nf][r], x2 = acc[m][nf + 4][r];
        float y1, y2;
        if (do_rope) {
          float c1 = cosb[t * HD + d], s1 = sinb[t * HD + d];
          float c2 = cosb[t * HD + d + 64], s2 = sinb[t * HD + d + 64];
          y1 = x1 * c1 - x2 * s1;
          y2 = x2 * c2 + x1 * s2;
        } else {
          y1 = x1; y2 = x2;
        }
        Out[(size_t)t * N + bn + d] = f2bf(y1);
        Out[(size_t)t * N + bn + d + 64] = f2bf(y2);
      }
}

// ---------------- 3-pass split projection GEMM + RoPE, hi/lo bf16 out -------
// C = (Ah+Al) @ (Wh+Wl)^T ~= Ah Wh + Ah Wl + Al Wh   (fp32-accurate)
__global__ __launch_bounds__(256) void proj3_gemm(
    const ushort_t* __restrict__ Ahi, const ushort_t* __restrict__ Alo,
    const ushort_t* __restrict__ Whi, const ushort_t* __restrict__ Wlo,
    ushort_t* __restrict__ Ohi, ushort_t* __restrict__ Olo,
    const float* __restrict__ cosb, const float* __restrict__ sinb, int N) {
  __shared__ char sm[65536];
  char* Ah = sm;
  char* Al = sm + 16384;
  char* Bh = sm + 32768;
  char* Bl = sm + 49152;
  const int tid = threadIdx.x, w = tid >> 6, lane = tid & 63;
  const int lo = lane & 15, hi = lane >> 4;
  const int bm = blockIdx.y * 128, bn = blockIdx.x * 128;
  f32x4 acc[2][8];
#pragma unroll
  for (int m = 0; m < 2; ++m)
#pragma unroll
    for (int n = 0; n < 8; ++n) acc[m][n] = f32x4{0.f, 0.f, 0.f, 0.f};

  for (int k0 = 0; k0 < HID; k0 += 64) {
#pragma unroll
    for (int p = 0; p < 4; ++p) {
      int idx = p * 256 + tid;
      int r = idx >> 3, c = idx & 7;
      size_t ga = (size_t)(bm + r) * HID + k0 + c * 8;
      size_t gb = (size_t)(bn + r) * HID + k0 + c * 8;
      int off = (r * 128 + c * 16) ^ ((r & 7) << 4);
      *(bf16x8*)(Ah + off) = *(const bf16x8*)(Ahi + ga);
      *(bf16x8*)(Al + off) = *(const bf16x8*)(Alo + ga);
      *(bf16x8*)(Bh + off) = *(const bf16x8*)(Whi + gb);
      *(bf16x8*)(Bl + off) = *(const bf16x8*)(Wlo + gb);
    }
    __syncthreads();
#pragma unroll
    for (int ks = 0; ks < 2; ++ks) {
      const int ko = ks * 64 + hi * 16;
      bf16x8 ah[2], al[2];
#pragma unroll
      for (int m = 0; m < 2; ++m) {
        int r = w * 32 + m * 16 + lo;
        int off = (r * 128 + ko) ^ ((r & 7) << 4);
        ah[m] = *(const bf16x8*)(Ah + off);
        al[m] = *(const bf16x8*)(Al + off);
      }
#pragma unroll
      for (int n = 0; n < 8; ++n) {
        int r = n * 16 + lo;
        int off = (r * 128 + ko) ^ ((r & 7) << 4);
        bf16x8 bh = *(const bf16x8*)(Bh + off);
        bf16x8 bl = *(const bf16x8*)(Bl + off);
#pragma unroll
        for (int m = 0; m < 2; ++m) {
          acc[m][n] = MFMA16(ah[m], bh, acc[m][n]);
          acc[m][n] = MFMA16(ah[m], bl, acc[m][n]);
          acc[m][n] = MFMA16(al[m], bh, acc[m][n]);
        }
      }
    }
    __syncthreads();
  }
  // fp32 RoPE epilogue, re-split to hi/lo
#pragma unroll
  for (int m = 0; m < 2; ++m)
#pragma unroll
    for (int nf = 0; nf < 4; ++nf)
#pragma unroll
      for (int r = 0; r < 4; ++r) {
        int t = bm + w * 32 + m * 16 + hi * 4 + r;
        int d = nf * 16 + lo;
        float x1 = acc[m][nf][r], x2 = acc[m][nf + 4][r];
        float c1 = cosb[t * HD + d], s1 = sinb[t * HD + d];
        float c2 = cosb[t * HD + d + 64], s2 = sinb[t * HD + d + 64];
        float y1 = x1 * c1 - x2 * s1;
        float y2 = x2 * c2 + x1 * s2;
        ushort_t h1 = f2bf(y1), h2 = f2bf(y2);
        size_t o1 = (size_t)t * N + bn + d;
        size_t o2 = o1 + 64;
        Ohi[o1] = h1; Olo[o1] = f2bf(y1 - bf2f(h1));
        Ohi[o2] = h2; Olo[o2] = f2bf(y2 - bf2f(h2));
      }
}

// ---------------- 3-pass spec GEMM: spec[h] = SCALE * Qs_h @ K_{h/4}^T ------
__global__ __launch_bounds__(256) void spec3_gemm(
    const ushort_t* __restrict__ Qhi, const ushort_t* __restrict__ Qlo,
    const ushort_t* __restrict__ Khi, const ushort_t* __restrict__ Klo,
    float* __restrict__ spec) {
  __shared__ char sm[65536];
  char* Ah = sm;
  char* Al = sm + 16384;
  char* Bh = sm + 32768;
  char* Bl = sm + 49152;
  const int tid = threadIdx.x, w = tid >> 6, lane = tid & 63;
  const int lo = lane & 15, hi = lane >> 4;
  const int h = blockIdx.z;
  const int bm = blockIdx.y * 128, bn = blockIdx.x * 128;
  const ushort_t* Abh = Qhi + h * HD;
  const ushort_t* Abl = Qlo + h * HD;
  const ushort_t* Bbh = Khi + (h >> 2) * HD;
  const ushort_t* Bbl = Klo + (h >> 2) * HD;
  float* C = spec + (size_t)h * S_LEN * S_LEN;
  f32x4 acc[2][8];
#pragma unroll
  for (int m = 0; m < 2; ++m)
#pragma unroll
    for (int n = 0; n < 8; ++n) acc[m][n] = f32x4{0.f, 0.f, 0.f, 0.f};

  for (int k0 = 0; k0 < HD; k0 += 64) {
#pragma unroll
    for (int p = 0; p < 4; ++p) {
      int idx = p * 256 + tid;
      int r = idx >> 3, c = idx & 7;
      size_t ga = (size_t)(bm + r) * HID + k0 + c * 8;
      size_t gb = (size_t)(bn + r) * KVW + k0 + c * 8;
      int off = (r * 128 + c * 16) ^ ((r & 7) << 4);
      *(bf16x8*)(Ah + off) = *(const bf16x8*)(Abh + ga);
      *(bf16x8*)(Al + off) = *(const bf16x8*)(Abl + ga);
      *(bf16x8*)(Bh + off) = *(const bf16x8*)(Bbh + gb);
      *(bf16x8*)(Bl + off) = *(const bf16x8*)(Bbl + gb);
    }
    __syncthreads();
#pragma unroll
    for (int ks = 0; ks < 2; ++ks) {
      const int ko = ks * 64 + hi * 16;
      bf16x8 ah[2], al[2];
#pragma unroll
      for (int m = 0; m < 2; ++m) {
        int r = w * 32 + m * 16 + lo;
        int off = (r * 128 + ko) ^ ((r & 7) << 4);
        ah[m] = *(const bf16x8*)(Ah + off);
        al[m] = *(const bf16x8*)(Al + off);
      }
#pragma unroll
      for (int n = 0; n < 8; ++n) {
        int r = n * 16 + lo;
        int off = (r * 128 + ko) ^ ((r & 7) << 4);
        bf16x8 bh = *(const bf16x8*)(Bh + off);
        bf16x8 bl = *(const bf16x8*)(Bl + off);
#pragma unroll
        for (int m = 0; m < 2; ++m) {
          acc[m][n] = MFMA16(ah[m], bh, acc[m][n]);
          acc[m][n] = MFMA16(ah[m], bl, acc[m][n]);
          acc[m][n] = MFMA16(al[m], bh, acc[m][n]);
        }
      }
    }
    __syncthreads();
  }
#pragma unroll
  for (int m = 0; m < 2; ++m)
#pragma unroll
    for (int nf = 0; nf < 8; ++nf)
#pragma unroll
      for (int r = 0; r < 4; ++r) {
        int t = bm + w * 32 + m * 16 + hi * 4 + r;
        int j = bn + nf * 16 + lo;
        C[(size_t)t * S_LEN + j] = acc[m][nf][r] * SCALE_C;
      }
}

// ---------------- output GEMM: out = AO @ Wo^T (fp32 out) -------------------
__global__ __launch_bounds__(256) void out_gemm(
    const ushort_t* __restrict__ A, const ushort_t* __restrict__ W,
    float* __restrict__ Out) {
  __shared__ char sm[32768];
  char* As = sm;
  char* Bs = sm + 16384;
  const int tid = threadIdx.x, w = tid >> 6, lane = tid & 63;
  const int lo = lane & 15, hi = lane >> 4;
  const int bm = blockIdx.y * 128, bn = blockIdx.x * 128;
  f32x4 acc[2][8];
#pragma unroll
  for (int m = 0; m < 2; ++m)
#pragma unroll
    for (int n = 0; n < 8; ++n) acc[m][n] = f32x4{0.f, 0.f, 0.f, 0.f};

  for (int k0 = 0; k0 < HID; k0 += 64) {
#pragma unroll
    for (int p = 0; p < 4; ++p) {
      int idx = p * 256 + tid;
      int r = idx >> 3, c = idx & 7;
      bf16x8 va = *(const bf16x8*)(A + (size_t)(bm + r) * HID + k0 + c * 8);
      *(bf16x8*)(As + ((r * 128 + c * 16) ^ ((r & 7) << 4))) = va;
      bf16x8 vb = *(const bf16x8*)(W + (size_t)(bn + r) * HID + k0 + c * 8);
      *(bf16x8*)(Bs + ((r * 128 + c * 16) ^ ((r & 7) << 4))) = vb;
    }
    __syncthreads();
#pragma unroll
    for (int ks = 0; ks < 2; ++ks) {
      const int ko = ks * 64 + hi * 16;
      bf16x8 af[2], bfr[8];
#pragma unroll
      for (int m = 0; m < 2; ++m) {
        int r = w * 32 + m * 16 + lo;
        af[m] = *(const bf16x8*)(As + ((r * 128 + ko) ^ ((r & 7) << 4)));
      }
#pragma unroll
      for (int n = 0; n < 8; ++n) {
        int r = n * 16 + lo;
        bfr[n] = *(const bf16x8*)(Bs + ((r * 128 + ko) ^ ((r & 7) << 4)));
      }
#pragma unroll
      for (int m = 0; m < 2; ++m)
#pragma unroll
        for (int n = 0; n < 8; ++n) acc[m][n] = MFMA16(af[m], bfr[n], acc[m][n]);
    }
    __syncthreads();
  }
#pragma unroll
  for (int m = 0; m < 2; ++m)
#pragma unroll
    for (int nf = 0; nf < 8; ++nf)
#pragma unroll
      for (int r = 0; r < 4; ++r) {
        int t = bm + w * 32 + m * 16 + hi * 4 + r;
        Out[(size_t)t * HID + bn + nf * 16 + lo] = acc[m][nf][r];
      }
}

// ---------------- per-(h,t): rowmax + count(>= max-ALPHA) -------------------
__global__ __launch_bounds__(256) void count_kernel(
    const float* __restrict__ spec, int* __restrict__ cnt) {
  const int t = blockIdx.x, h = blockIdx.y, tid = threadIdx.x;
  __shared__ float redf[256];
  __shared__ int redi[256];
  const float* row = spec + ((size_t)h * S_LEN + t) * S_LEN;
  float mx = -1e30f;
  for (int j = tid; j <= t; j += 256) mx = fmaxf(mx, row[j]);
  redf[tid] = mx; __syncthreads();
  for (int s = 128; s; s >>= 1) { if (tid < s) redf[tid] = fmaxf(redf[tid], redf[tid + s]); __syncthreads(); }
  const float cut = redf[0] - ALPHA_C;
  int c = 0;
  for (int j = tid; j <= t; j += 256) c += (row[j] >= cut) ? 1 : 0;
  redi[tid] = c; __syncthreads();
  for (int s = 128; s; s >>= 1) { if (tid < s) redi[tid] += redi[tid + s]; __syncthreads(); }
  if (tid == 0) cnt[h * S_LEN + t] = redi[0];
}

__global__ __launch_bounds__(256) void fn_kernel(
    const int* __restrict__ cnt, int* __restrict__ fn) {
  int t = blockIdx.x * 256 + threadIdx.x;
  if (t >= S_LEN) return;
  int s = 0;
#pragma unroll
  for (int h = 0; h < NHEADS; ++h) s += cnt[h * S_LEN + t];
  int f = s >> 4;
  fn[t] = f > FETCH_MAX ? FETCH_MAX : f;
}

// ---------------- exact k-th largest per (h,t) via radix select -------------
__global__ __launch_bounds__(256) void thr_kernel(
    const float* __restrict__ spec, const int* __restrict__ fn,
    float* __restrict__ thr) {
  const int t = blockIdx.x, h = blockIdx.y;
  if (t < FETCH_MAX) return;
  const int tid = threadIdx.x;
  __shared__ int hist[256];
  __shared__ unsigned pref_s;
  __shared__ int k_s;
  const float* row = spec + ((size_t)h * S_LEN + t) * S_LEN;
  int k = fn[t];
  unsigned prefix = 0;
  for (int r = 3; r >= 0; --r) {
    hist[tid] = 0;
    __syncthreads();
    const int shift = r * 8;
    for (int j = tid; j <= t; j += 256) {
      unsigned bits = __float_as_uint(row[j]);
      unsigned u = (bits & 0x80000000u) ? ~bits : (bits | 0x80000000u);
      bool cand = (r == 3) || ((u >> (shift + 8)) == (prefix >> (shift + 8)));
      if (cand) atomicAdd(&hist[(u >> shift) & 255], 1);
    }
    __syncthreads();
    if (tid == 0) {
      int cum = 0, b = 255;
      for (; b >= 0; --b) { cum += hist[b]; if (cum >= k) break; }
      k_s = k - (cum - hist[b]);
      pref_s = prefix | ((unsigned)b << shift);
    }
    __syncthreads();
    prefix = pref_s; k = k_s;
    __syncthreads();
  }
  if (tid == 0) {
    unsigned u = prefix;
    unsigned bits = (u & 0x80000000u) ? (u & 0x7fffffffu) : ~u;
    thr[h * S_LEN + t] = __uint_as_float(bits);
  }
}

// ---------------- flash-style MFMA attention --------------------------------
__global__ __launch_bounds__(256) void attn_mfma(
    const ushort_t* __restrict__ Qbf, const ushort_t* __restrict__ Kbf,
    const ushort_t* __restrict__ Vbf, const float* __restrict__ spec,
    const float* __restrict__ thr, ushort_t* __restrict__ AO) {
  __shared__ char sm[41984];
  const int tid = threadIdx.x, w = tid >> 6, lane = tid & 63;
  const int lo = lane & 15, hi = lane >> 4;
  const int rt = blockIdx.x, h = blockIdx.y;
  const int kvh = h >> 2;
  const int qrow = rt * 64 + w * 16 + lo;
  const int t0 = rt * 64 + w * 16 + hi * 4;

  bf16x8 qf[4];
  const ushort_t* qp = Qbf + (size_t)qrow * HID + h * HD;
#pragma unroll
  for (int ks = 0; ks < 4; ++ks) qf[ks] = *(const bf16x8*)(qp + ks * 32 + hi * 8);

  float thrv[4], mrun[4], lrun[4];
  f32x4 o[8];
#pragma unroll
  for (int r = 0; r < 4; ++r) {
    thrv[r] = thr[h * S_LEN + t0 + r];
    mrun[r] = -1e30f;
    lrun[r] = 0.f;
  }
#pragma unroll
  for (int n = 0; n < 8; ++n) o[n] = f32x4{0.f, 0.f, 0.f, 0.f};

  const int ntiles = rt + 1;
  for (int jt = 0; jt < ntiles; ++jt) {
    const int j0 = jt * 64;
#pragma unroll
    for (int p = 0; p < 4; ++p) {
      int idx = p * 256 + tid;
      int r = idx >> 4, c = idx & 15;
      bf16x8 v = *(const bf16x8*)(Kbf + (size_t)(j0 + r) * KVW + kvh * HD + c * 8);
      *(bf16x8*)(sm + ((r * 256 + c * 16) ^ ((r & 7) << 4))) = v;
    }
#pragma unroll
    for (int p = 0; p < 4; ++p) {
      int idx = p * 256 + tid;
      int j = idx & 63, dc = idx >> 6;
      bf16x8 v = *(const bf16x8*)(Vbf + (size_t)(j0 + j) * KVW + kvh * HD + dc * 8);
#pragma unroll
      for (int i = 0; i < 8; ++i) {
        int d = dc * 8 + i;
        *(ushort_t*)(sm + 16384 + ((d * 128 + j * 2) ^ ((d & 7) << 4))) = (ushort_t)v[i];
      }
    }
    __syncthreads();
    f32x4 s[4];
#pragma unroll
    for (int nf = 0; nf < 4; ++nf) {
      f32x4 a = f32x4{0.f, 0.f, 0.f, 0.f};
#pragma unroll
      for (int ks = 0; ks < 4; ++ks) {
        int r = nf * 16 + lo;
        bf16x8 kfr = *(const bf16x8*)(sm + ((r * 256 + ks * 64 + hi * 16) ^ ((r & 7) << 4)));
        a = MFMA16(qf[ks], kfr, a);
      }
      s[nf] = a;
    }
    float pvv[4][4];
    float tmax[4] = {-1e30f, -1e30f, -1e30f, -1e30f};
#pragma unroll
    for (int nf = 0; nf < 4; ++nf) {
      int j = j0 + nf * 16 + lo;
#pragma unroll
      for (int r = 0; r < 4; ++r) {
        int t = t0 + r;
        float sc = s[nf][r] * SCALE_C;
        bool ok = (j <= t);
        if (ok && t >= FETCH_MAX) {
          float sv = spec[(size_t)h * (S_LEN * S_LEN) + (size_t)t * S_LEN + j];
          ok = (sv >= thrv[r]);
        }
        float val = ok ? sc : -1e30f;
        pvv[nf][r] = val;
        tmax[r] = fmaxf(tmax[r], val);
      }
    }
#pragma unroll
    for (int r = 0; r < 4; ++r) {
      float m = tmax[r];
      m = fmaxf(m, __shfl_xor(m, 1));
      m = fmaxf(m, __shfl_xor(m, 2));
      m = fmaxf(m, __shfl_xor(m, 4));
      m = fmaxf(m, __shfl_xor(m, 8));
      tmax[r] = m;
    }
    float alpha[4];
#pragma unroll
    for (int r = 0; r < 4; ++r) {
      float mnew = fmaxf(mrun[r], tmax[r]);
      alpha[r] = __expf(mrun[r] - mnew);
      mrun[r] = mnew;
    }
    float lsum[4] = {0.f, 0.f, 0.f, 0.f};
#pragma unroll
    for (int nf = 0; nf < 4; ++nf)
#pragma unroll
      for (int r = 0; r < 4; ++r) {
        float v2 = pvv[nf][r];
        float p = (v2 > -1e29f) ? __expf(v2 - mrun[r]) : 0.f;
        pvv[nf][r] = p;
        lsum[r] += p;
      }
#pragma unroll
    for (int r = 0; r < 4; ++r) {
      float ls = lsum[r];
      ls += __shfl_xor(ls, 1);
      ls += __shfl_xor(ls, 2);
      ls += __shfl_xor(ls, 4);
      ls += __shfl_xor(ls, 8);
      lrun[r] = lrun[r] * alpha[r] + ls;
#pragma unroll
      for (int n = 0; n < 8; ++n) o[n][r] *= alpha[r];
    }
    char* pb = sm + 32768 + w * 2304;
#pragma unroll
    for (int nf = 0; nf < 4; ++nf)
#pragma unroll
      for (int r = 0; r < 4; ++r)
        *(ushort_t*)(pb + (hi * 4 + r) * 144 + (nf * 16 + lo) * 2) = f2bf(pvv[nf][r]);
#pragma unroll
    for (int ks = 0; ks < 2; ++ks) {
      bf16x8 pa = *(const bf16x8*)(pb + lo * 144 + ks * 64 + hi * 16);
#pragma unroll
      for (int df = 0; df < 8; ++df) {
        int d = df * 16 + lo;
        bf16x8 vb = *(const bf16x8*)(sm + 16384 + ((d * 128 + ks * 64 + hi * 16) ^ ((d & 7) << 4)));
        o[df] = MFMA16(pa, vb, o[df]);
      }
    }
    __syncthreads();
  }
#pragma unroll
  for (int r = 0; r < 4; ++r) {
    float inv = 1.0f / lrun[r];
    int t = t0 + r;
#pragma unroll
    for (int df = 0; df < 8; ++df)
      AO[(size_t)t * HID + h * HD + df * 16 + lo] = f2bf(o[df][r] * inv);
  }
}

extern "C" void kernel_launch(void* const* d_in, const int* in_sizes, int n_in,
                              void* d_out, int out_size, void* d_ws, size_t ws_size,
                              hipStream_t stream) {
  const float* hidden = (const float*)d_in[0];
  const float* prev   = (const float*)d_in[1];
  const float* cosb   = (const float*)d_in[2];
  const float* sinb   = (const float*)d_in[3];
  const float* Wq     = (const float*)d_in[4];
  const float* Wk     = (const float*)d_in[5];
  const float* Wv     = (const float*)d_in[6];
  const float* Wo     = (const float*)d_in[7];
  float* out = (float*)d_out;

  char* ws = (char*)d_ws;
  const size_t MB = 1u << 20;
  // spec region [0, 64MB); early hi/lo buffers live inside it (dead before
  // spec3 writes), then spec3 overwrites.
  float*    spec = (float*)(ws + 0);
  ushort_t* phi  = (ushort_t*)(ws + 0);          // prev hi   4MB
  ushort_t* plo  = (ushort_t*)(ws + 4 * MB);     // prev lo   4MB
  ushort_t* wqhi = (ushort_t*)(ws + 8 * MB);     // Wq hi     8MB
  ushort_t* wqlo = (ushort_t*)(ws + 16 * MB);    // Wq lo     8MB
  ushort_t* wkhi = (ushort_t*)(ws + 24 * MB);    // Wk hi     2MB
  ushort_t* wklo = (ushort_t*)(ws + 26 * MB);    // Wk lo     2MB
  // persistent region
  ushort_t* hhi  = (ushort_t*)(ws + 64 * MB);    // hidden hi 4MB (dead after V)
  ushort_t* hlo  = (ushort_t*)(ws + 68 * MB);    // hidden lo 4MB
  ushort_t* qbf  = (ushort_t*)(ws + 72 * MB);    // Q bf16    4MB
  ushort_t* qshi = (ushort_t*)(ws + 76 * MB);    // Qs hi     4MB (dead after spec)
  ushort_t* qslo = (ushort_t*)(ws + 80 * MB);    // Qs lo     4MB (dead after spec)
  ushort_t* khi  = (ushort_t*)(ws + 84 * MB);    // K hi      1MB
  ushort_t* klo  = (ushort_t*)(ws + 85 * MB);    // K lo      1MB
  ushort_t* vbf  = (ushort_t*)(ws + 86 * MB);    // V bf16    1MB
  ushort_t* wvbf = (ushort_t*)(ws + 87 * MB);    // Wv bf16   2MB
  int*   cnt = (int*)  (ws + 89 * MB);
  int*   fn  = (int*)  (ws + 89 * MB + (64u << 10));
  float* thr = (float*)(ws + 89 * MB + (80u << 10));
  ushort_t* wobf = (ushort_t*)(ws + 76 * MB);    // Wo bf16 8MB (over qshi/qslo, after spec)
  ushort_t* aobf = (ushort_t*)(ws + 64 * MB);    // AO bf16 4MB (over hhi, after V)

  // conversions
  to_bf16_split<<<1024, 256, 0, stream>>>(hidden, hhi, hlo, S_LEN * HID);
  to_bf16_split<<<1024, 256, 0, stream>>>(prev, phi, plo, S_LEN * HID);
  to_bf16_split<<<2048, 256, 0, stream>>>(Wq, wqhi, wqlo, HID * HID);
  to_bf16_split<<<512, 256, 0, stream>>>(Wk, wkhi, wklo, KVW * HID);
  to_bf16<<<512, 256, 0, stream>>>(Wv, wvbf, KVW * HID);

  // projections
  proj_gemm<<<dim3(16, 8), 256, 0, stream>>>(hhi, wqhi, qbf, cosb, sinb, HID, 1);
  proj3_gemm<<<dim3(16, 8), 256, 0, stream>>>(phi, plo, wqhi, wqlo, qshi, qslo, cosb, sinb, HID);
  proj3_gemm<<<dim3(4, 8), 256, 0, stream>>>(hhi, hlo, wkhi, wklo, khi, klo, cosb, sinb, KVW);
  proj_gemm<<<dim3(4, 8), 256, 0, stream>>>(hhi, wvbf, vbf, cosb, sinb, KVW, 0);

  // speculative scores (fp32-accurate)
  spec3_gemm<<<dim3(8, 8, NHEADS), 256, 0, stream>>>(qshi, qslo, khi, klo, spec);

  // mask statistics (exact on fp32 spec)
  count_kernel<<<dim3(S_LEN, NHEADS), 256, 0, stream>>>(spec, cnt);
  fn_kernel<<<S_LEN / 256, 256, 0, stream>>>(cnt, fn);
  thr_kernel<<<dim3(S_LEN, NHEADS), 256, 0, stream>>>(spec, fn, thr);

  // Wo conversion into region freed after spec3 (qshi/qslo dead)
  to_bf16<<<2048, 256, 0, stream>>>(Wo, wobf, HID * HID);

  // attention
  attn_mfma<<<dim3(16, NHEADS), 256, 0, stream>>>(qbf, khi, vbf, spec, thr, aobf);

  // output projection
  out_gemm<<<dim3(16, 8), 256, 0, stream>>>(aobf, wobf, out);
}

// Round 4
// 404.763 us; speedup vs baseline: 4.8440x; 1.5488x over previous
//
#include <hip/hip_runtime.h>
#include <hip/hip_bf16.h>

#define S_LEN 1024
#define HID 2048
#define NHEADS 16
#define KVHEADS 4
#define HD 128
#define KVW 512
#define FETCH_MAX 204
#define ALPHA_C 5.0f
#define SCALE_C 0.08838834764831845f

typedef __attribute__((ext_vector_type(8))) short bf16x8;
typedef __attribute__((ext_vector_type(4))) float f32x4;
typedef unsigned short ushort_t;

#define MFMA16(a, b, c) __builtin_amdgcn_mfma_f32_16x16x32_bf16(a, b, c, 0, 0, 0)

__device__ __forceinline__ ushort_t f2bf(float f) {
  unsigned u = __float_as_uint(f);
  return (ushort_t)((u + 0x7fffu + ((u >> 16) & 1u)) >> 16);
}
__device__ __forceinline__ float bf2f(ushort_t h) {
  return __uint_as_float(((unsigned)h) << 16);
}

// ---------------- fp32 -> bf16, 8 elems/thread ------------------------------
__global__ __launch_bounds__(256) void to_bf16(const float* __restrict__ in,
                                               ushort_t* __restrict__ out, int n) {
  int i = (blockIdx.x * 256 + threadIdx.x) * 8;
  if (i >= n) return;
  float4 a = *(const float4*)(in + i);
  float4 b = *(const float4*)(in + i + 4);
  bf16x8 v;
  v[0] = (short)f2bf(a.x); v[1] = (short)f2bf(a.y);
  v[2] = (short)f2bf(a.z); v[3] = (short)f2bf(a.w);
  v[4] = (short)f2bf(b.x); v[5] = (short)f2bf(b.y);
  v[6] = (short)f2bf(b.z); v[7] = (short)f2bf(b.w);
  *(bf16x8*)(out + i) = v;
}

// ---------------- fp32 -> bf16 hi/lo split, 8 elems/thread ------------------
__global__ __launch_bounds__(256) void to_bf16_split(const float* __restrict__ in,
                                                     ushort_t* __restrict__ hi,
                                                     ushort_t* __restrict__ lo, int n) {
  int i = (blockIdx.x * 256 + threadIdx.x) * 8;
  if (i >= n) return;
  bf16x8 vh, vl;
#pragma unroll
  for (int q = 0; q < 8; ++q) {
    float x = in[i + q];
    ushort_t h = f2bf(x);
    vh[q] = (short)h;
    vl[q] = (short)f2bf(x - bf2f(h));
  }
  *(bf16x8*)(hi + i) = vh;
  *(bf16x8*)(lo + i) = vl;
}

// ---------------- 1-pass projection GEMM + optional RoPE, bf16 out ----------
__global__ __launch_bounds__(256) void proj_gemm(
    const ushort_t* __restrict__ A, const ushort_t* __restrict__ W,
    ushort_t* __restrict__ Out, const float* __restrict__ cosb,
    const float* __restrict__ sinb, int N, int do_rope) {
  __shared__ char sm[32768];
  char* As = sm;
  char* Bs = sm + 16384;
  const int tid = threadIdx.x, w = tid >> 6, lane = tid & 63;
  const int lo = lane & 15, hi = lane >> 4;
  const int bm = blockIdx.y * 128, bn = blockIdx.x * 128;
  f32x4 acc[2][8];
#pragma unroll
  for (int m = 0; m < 2; ++m)
#pragma unroll
    for (int n = 0; n < 8; ++n) acc[m][n] = f32x4{0.f, 0.f, 0.f, 0.f};

  for (int k0 = 0; k0 < HID; k0 += 64) {
#pragma unroll
    for (int p = 0; p < 4; ++p) {
      int idx = p * 256 + tid;
      int r = idx >> 3, c = idx & 7;
      bf16x8 va = *(const bf16x8*)(A + (size_t)(bm + r) * HID + k0 + c * 8);
      *(bf16x8*)(As + ((r * 128 + c * 16) ^ ((r & 7) << 4))) = va;
      bf16x8 vb = *(const bf16x8*)(W + (size_t)(bn + r) * HID + k0 + c * 8);
      *(bf16x8*)(Bs + ((r * 128 + c * 16) ^ ((r & 7) << 4))) = vb;
    }
    __syncthreads();
#pragma unroll
    for (int ks = 0; ks < 2; ++ks) {
      const int ko = ks * 64 + hi * 16;
      bf16x8 af[2], bfr[8];
#pragma unroll
      for (int m = 0; m < 2; ++m) {
        int r = w * 32 + m * 16 + lo;
        af[m] = *(const bf16x8*)(As + ((r * 128 + ko) ^ ((r & 7) << 4)));
      }
#pragma unroll
      for (int n = 0; n < 8; ++n) {
        int r = n * 16 + lo;
        bfr[n] = *(const bf16x8*)(Bs + ((r * 128 + ko) ^ ((r & 7) << 4)));
      }
#pragma unroll
      for (int m = 0; m < 2; ++m)
#pragma unroll
        for (int n = 0; n < 8; ++n) acc[m][n] = MFMA16(af[m], bfr[n], acc[m][n]);
    }
    __syncthreads();
  }
#pragma unroll
  for (int m = 0; m < 2; ++m)
#pragma unroll
    for (int nf = 0; nf < 4; ++nf)
#pragma unroll
      for (int r = 0; r < 4; ++r) {
        int t = bm + w * 32 + m * 16 + hi * 4 + r;
        int d = nf * 16 + lo;
        float x1 = acc[m][nf][r], x2 = acc[m][nf + 4][r];
        float y1, y2;
        if (do_rope) {
          float c1 = cosb[t * HD + d], s1 = sinb[t * HD + d];
          float c2 = cosb[t * HD + d + 64], s2 = sinb[t * HD + d + 64];
          y1 = x1 * c1 - x2 * s1;
          y2 = x2 * c2 + x1 * s2;
        } else {
          y1 = x1; y2 = x2;
        }
        Out[(size_t)t * N + bn + d] = f2bf(y1);
        Out[(size_t)t * N + bn + d + 64] = f2bf(y2);
      }
}

// ---------------- 3-pass split projection GEMM + RoPE, hi/lo bf16 out -------
__global__ __launch_bounds__(256) void proj3_gemm(
    const ushort_t* __restrict__ Ahi, const ushort_t* __restrict__ Alo,
    const ushort_t* __restrict__ Whi, const ushort_t* __restrict__ Wlo,
    ushort_t* __restrict__ Ohi, ushort_t* __restrict__ Olo,
    const float* __restrict__ cosb, const float* __restrict__ sinb, int N) {
  __shared__ char sm[65536];
  char* Ah = sm;
  char* Al = sm + 16384;
  char* Bh = sm + 32768;
  char* Bl = sm + 49152;
  const int tid = threadIdx.x, w = tid >> 6, lane = tid & 63;
  const int lo = lane & 15, hi = lane >> 4;
  const int bm = blockIdx.y * 128, bn = blockIdx.x * 128;
  f32x4 acc[2][8];
#pragma unroll
  for (int m = 0; m < 2; ++m)
#pragma unroll
    for (int n = 0; n < 8; ++n) acc[m][n] = f32x4{0.f, 0.f, 0.f, 0.f};

  for (int k0 = 0; k0 < HID; k0 += 64) {
#pragma unroll
    for (int p = 0; p < 4; ++p) {
      int idx = p * 256 + tid;
      int r = idx >> 3, c = idx & 7;
      size_t ga = (size_t)(bm + r) * HID + k0 + c * 8;
      size_t gb = (size_t)(bn + r) * HID + k0 + c * 8;
      int off = (r * 128 + c * 16) ^ ((r & 7) << 4);
      *(bf16x8*)(Ah + off) = *(const bf16x8*)(Ahi + ga);
      *(bf16x8*)(Al + off) = *(const bf16x8*)(Alo + ga);
      *(bf16x8*)(Bh + off) = *(const bf16x8*)(Whi + gb);
      *(bf16x8*)(Bl + off) = *(const bf16x8*)(Wlo + gb);
    }
    __syncthreads();
#pragma unroll
    for (int ks = 0; ks < 2; ++ks) {
      const int ko = ks * 64 + hi * 16;
      bf16x8 ah[2], al[2];
#pragma unroll
      for (int m = 0; m < 2; ++m) {
        int r = w * 32 + m * 16 + lo;
        int off = (r * 128 + ko) ^ ((r & 7) << 4);
        ah[m] = *(const bf16x8*)(Ah + off);
        al[m] = *(const bf16x8*)(Al + off);
      }
#pragma unroll
      for (int n = 0; n < 8; ++n) {
        int r = n * 16 + lo;
        int off = (r * 128 + ko) ^ ((r & 7) << 4);
        bf16x8 bh = *(const bf16x8*)(Bh + off);
        bf16x8 bl = *(const bf16x8*)(Bl + off);
#pragma unroll
        for (int m = 0; m < 2; ++m) {
          acc[m][n] = MFMA16(ah[m], bh, acc[m][n]);
          acc[m][n] = MFMA16(ah[m], bl, acc[m][n]);
          acc[m][n] = MFMA16(al[m], bh, acc[m][n]);
        }
      }
    }
    __syncthreads();
  }
#pragma unroll
  for (int m = 0; m < 2; ++m)
#pragma unroll
    for (int nf = 0; nf < 4; ++nf)
#pragma unroll
      for (int r = 0; r < 4; ++r) {
        int t = bm + w * 32 + m * 16 + hi * 4 + r;
        int d = nf * 16 + lo;
        float x1 = acc[m][nf][r], x2 = acc[m][nf + 4][r];
        float c1 = cosb[t * HD + d], s1 = sinb[t * HD + d];
        float c2 = cosb[t * HD + d + 64], s2 = sinb[t * HD + d + 64];
        float y1 = x1 * c1 - x2 * s1;
        float y2 = x2 * c2 + x1 * s2;
        ushort_t h1 = f2bf(y1), h2 = f2bf(y2);
        size_t o1 = (size_t)t * N + bn + d;
        size_t o2 = o1 + 64;
        Ohi[o1] = h1; Olo[o1] = f2bf(y1 - bf2f(h1));
        Ohi[o2] = h2; Olo[o2] = f2bf(y2 - bf2f(h2));
      }
}

// ---------------- 3-pass spec GEMM: spec[h] = SCALE * Qs_h @ K_{h/4}^T ------
__global__ __launch_bounds__(256) void spec3_gemm(
    const ushort_t* __restrict__ Qhi, const ushort_t* __restrict__ Qlo,
    const ushort_t* __restrict__ Khi, const ushort_t* __restrict__ Klo,
    float* __restrict__ spec) {
  __shared__ char sm[65536];
  char* Ah = sm;
  char* Al = sm + 16384;
  char* Bh = sm + 32768;
  char* Bl = sm + 49152;
  const int tid = threadIdx.x, w = tid >> 6, lane = tid & 63;
  const int lo = lane & 15, hi = lane >> 4;
  const int h = blockIdx.z;
  const int bm = blockIdx.y * 128, bn = blockIdx.x * 128;
  const ushort_t* Abh = Qhi + h * HD;
  const ushort_t* Abl = Qlo + h * HD;
  const ushort_t* Bbh = Khi + (h >> 2) * HD;
  const ushort_t* Bbl = Klo + (h >> 2) * HD;
  float* C = spec + (size_t)h * S_LEN * S_LEN;
  f32x4 acc[2][8];
#pragma unroll
  for (int m = 0; m < 2; ++m)
#pragma unroll
    for (int n = 0; n < 8; ++n) acc[m][n] = f32x4{0.f, 0.f, 0.f, 0.f};

  for (int k0 = 0; k0 < HD; k0 += 64) {
#pragma unroll
    for (int p = 0; p < 4; ++p) {
      int idx = p * 256 + tid;
      int r = idx >> 3, c = idx & 7;
      size_t ga = (size_t)(bm + r) * HID + k0 + c * 8;
      size_t gb = (size_t)(bn + r) * KVW + k0 + c * 8;
      int off = (r * 128 + c * 16) ^ ((r & 7) << 4);
      *(bf16x8*)(Ah + off) = *(const bf16x8*)(Abh + ga);
      *(bf16x8*)(Al + off) = *(const bf16x8*)(Abl + ga);
      *(bf16x8*)(Bh + off) = *(const bf16x8*)(Bbh + gb);
      *(bf16x8*)(Bl + off) = *(const bf16x8*)(Bbl + gb);
    }
    __syncthreads();
#pragma unroll
    for (int ks = 0; ks < 2; ++ks) {
      const int ko = ks * 64 + hi * 16;
      bf16x8 ah[2], al[2];
#pragma unroll
      for (int m = 0; m < 2; ++m) {
        int r = w * 32 + m * 16 + lo;
        int off = (r * 128 + ko) ^ ((r & 7) << 4);
        ah[m] = *(const bf16x8*)(Ah + off);
        al[m] = *(const bf16x8*)(Al + off);
      }
#pragma unroll
      for (int n = 0; n < 8; ++n) {
        int r = n * 16 + lo;
        int off = (r * 128 + ko) ^ ((r & 7) << 4);
        bf16x8 bh = *(const bf16x8*)(Bh + off);
        bf16x8 bl = *(const bf16x8*)(Bl + off);
#pragma unroll
        for (int m = 0; m < 2; ++m) {
          acc[m][n] = MFMA16(ah[m], bh, acc[m][n]);
          acc[m][n] = MFMA16(ah[m], bl, acc[m][n]);
          acc[m][n] = MFMA16(al[m], bh, acc[m][n]);
        }
      }
    }
    __syncthreads();
  }
#pragma unroll
  for (int m = 0; m < 2; ++m)
#pragma unroll
    for (int nf = 0; nf < 8; ++nf)
#pragma unroll
      for (int r = 0; r < 4; ++r) {
        int t = bm + w * 32 + m * 16 + hi * 4 + r;
        int j = bn + nf * 16 + lo;
        C[(size_t)t * S_LEN + j] = acc[m][nf][r] * SCALE_C;
      }
}

// ---------------- output GEMM: out = AO @ Wo^T (fp32 out) -------------------
__global__ __launch_bounds__(256) void out_gemm(
    const ushort_t* __restrict__ A, const ushort_t* __restrict__ W,
    float* __restrict__ Out) {
  __shared__ char sm[32768];
  char* As = sm;
  char* Bs = sm + 16384;
  const int tid = threadIdx.x, w = tid >> 6, lane = tid & 63;
  const int lo = lane & 15, hi = lane >> 4;
  const int bm = blockIdx.y * 128, bn = blockIdx.x * 128;
  f32x4 acc[2][8];
#pragma unroll
  for (int m = 0; m < 2; ++m)
#pragma unroll
    for (int n = 0; n < 8; ++n) acc[m][n] = f32x4{0.f, 0.f, 0.f, 0.f};

  for (int k0 = 0; k0 < HID; k0 += 64) {
#pragma unroll
    for (int p = 0; p < 4; ++p) {
      int idx = p * 256 + tid;
      int r = idx >> 3, c = idx & 7;
      bf16x8 va = *(const bf16x8*)(A + (size_t)(bm + r) * HID + k0 + c * 8);
      *(bf16x8*)(As + ((r * 128 + c * 16) ^ ((r & 7) << 4))) = va;
      bf16x8 vb = *(const bf16x8*)(W + (size_t)(bn + r) * HID + k0 + c * 8);
      *(bf16x8*)(Bs + ((r * 128 + c * 16) ^ ((r & 7) << 4))) = vb;
    }
    __syncthreads();
#pragma unroll
    for (int ks = 0; ks < 2; ++ks) {
      const int ko = ks * 64 + hi * 16;
      bf16x8 af[2], bfr[8];
#pragma unroll
      for (int m = 0; m < 2; ++m) {
        int r = w * 32 + m * 16 + lo;
        af[m] = *(const bf16x8*)(As + ((r * 128 + ko) ^ ((r & 7) << 4)));
      }
#pragma unroll
      for (int n = 0; n < 8; ++n) {
        int r = n * 16 + lo;
        bfr[n] = *(const bf16x8*)(Bs + ((r * 128 + ko) ^ ((r & 7) << 4)));
      }
#pragma unroll
      for (int m = 0; m < 2; ++m)
#pragma unroll
        for (int n = 0; n < 8; ++n) acc[m][n] = MFMA16(af[m], bfr[n], acc[m][n]);
    }
    __syncthreads();
  }
#pragma unroll
  for (int m = 0; m < 2; ++m)
#pragma unroll
    for (int nf = 0; nf < 8; ++nf)
#pragma unroll
      for (int r = 0; r < 4; ++r) {
        int t = bm + w * 32 + m * 16 + hi * 4 + r;
        Out[(size_t)t * HID + bn + nf * 16 + lo] = acc[m][nf][r];
      }
}

// ---------------- per-(h,t>=204): rowmax + count(>= max-ALPHA), LDS-cached --
__global__ __launch_bounds__(256) void count_kernel(
    const float* __restrict__ spec, int* __restrict__ cnt) {
  const int t = blockIdx.x + FETCH_MAX, h = blockIdx.y, tid = threadIdx.x;
  const int w = tid >> 6, lane = tid & 63;
  __shared__ float rowc[1024];
  __shared__ float wmax[4];
  __shared__ int wcnt[4];
  const float* row = spec + ((size_t)h * S_LEN + t) * S_LEN;
  float mx = -1e30f;
  for (int j = tid; j <= t; j += 256) {
    float v = row[j];
    rowc[j] = v;
    mx = fmaxf(mx, v);
  }
#pragma unroll
  for (int d = 1; d < 64; d <<= 1) mx = fmaxf(mx, __shfl_xor(mx, d));
  if (lane == 0) wmax[w] = mx;
  __syncthreads();
  const float cut = fmaxf(fmaxf(wmax[0], wmax[1]), fmaxf(wmax[2], wmax[3])) - ALPHA_C;
  int c = 0;
  for (int j = tid; j <= t; j += 256) c += (rowc[j] >= cut) ? 1 : 0;
#pragma unroll
  for (int d = 1; d < 64; d <<= 1) c += __shfl_xor(c, d);
  if (lane == 0) wcnt[w] = c;
  __syncthreads();
  if (tid == 0) cnt[h * S_LEN + t] = wcnt[0] + wcnt[1] + wcnt[2] + wcnt[3];
}

// fn[t] = min( floor(mean_h cnt), FETCH_MAX ), only for t >= FETCH_MAX
__global__ __launch_bounds__(256) void fn_kernel(
    const int* __restrict__ cnt, int* __restrict__ fn) {
  int t = FETCH_MAX + blockIdx.x * 256 + threadIdx.x;
  if (t >= S_LEN) return;
  int s = 0;
#pragma unroll
  for (int h = 0; h < NHEADS; ++h) s += cnt[h * S_LEN + t];
  int f = s >> 4;
  fn[t] = f > FETCH_MAX ? FETCH_MAX : f;
}

// ---- wave-0 parallel bin select: largest bin b with suffix-count >= k ------
__device__ __forceinline__ void select_bin(const int* hist, int k, int w, int lane,
                                           int* sh_bin, int* sh_k) {
  if (w == 0) {
    const int base = 252 - 4 * lane;       // lane 0 owns bins 252..255 (top)
    int c0 = hist[base], c1 = hist[base + 1], c2 = hist[base + 2], c3 = hist[base + 3];
    int s = c0 + c1 + c2 + c3;
    int p = s;
#pragma unroll
    for (int d = 1; d < 64; d <<= 1) {
      int q = __shfl_up(p, d);
      if (lane >= d) p += q;
    }
    unsigned long long m = __ballot(p >= k);
    int lsel = __ffsll((unsigned long long)m) - 1;
    if (lane == lsel) {
      int cum = p - s;                     // count in bins above this group
      int b;
      if (cum + c3 >= k) { b = base + 3; }
      else if (cum + c3 + c2 >= k) { cum += c3; b = base + 2; }
      else if (cum + c3 + c2 + c1 >= k) { cum += c3 + c2; b = base + 1; }
      else { cum += c3 + c2 + c1; b = base; }
      *sh_bin = b;
      *sh_k = k - cum;
    }
  }
}

// ---------------- exact k-th largest -> bitmask, LDS-cached radix select ----
// maskb[h][t][16] u64 words; bit j set iff spec[h][t][j] >= kth-largest (ties in).
__global__ __launch_bounds__(256) void thr_kernel(
    const float* __restrict__ spec, const int* __restrict__ fn,
    unsigned long long* __restrict__ maskb) {
  const int t = blockIdx.x + FETCH_MAX, h = blockIdx.y;
  const int tid = threadIdx.x, w = tid >> 6, lane = tid & 63;
  __shared__ unsigned rowk[1024];
  __shared__ unsigned candA[1024];
  __shared__ unsigned candB[1024];
  __shared__ int hist4[4][256];
  __shared__ int hist[256];
  __shared__ int sh_bin, sh_k, sh_cnt;
  const float* row = spec + ((size_t)h * S_LEN + t) * S_LEN;
  const int n0 = t + 1;
  int k = fn[t];
  hist4[0][tid] = 0; hist4[1][tid] = 0; hist4[2][tid] = 0; hist4[3][tid] = 0;
  if (tid == 0) sh_cnt = 0;
  __syncthreads();
  // round 1: load + key-map + per-wave hist on byte3
  for (int j = tid; j < n0; j += 256) {
    unsigned bits = __float_as_uint(row[j]);
    unsigned u = (bits & 0x80000000u) ? ~bits : (bits | 0x80000000u);
    rowk[j] = u;
    atomicAdd(&hist4[w][u >> 24], 1);
  }
  __syncthreads();
  hist[tid] = hist4[0][tid] + hist4[1][tid] + hist4[2][tid] + hist4[3][tid];
  __syncthreads();
  select_bin(hist, k, w, lane, &sh_bin, &sh_k);
  __syncthreads();
  unsigned prefix = (unsigned)sh_bin << 24;
  k = sh_k;
  {
    const unsigned bsel = (unsigned)sh_bin;
    for (int j = tid; j < n0; j += 256) {
      unsigned u = rowk[j];
      if ((u >> 24) == bsel) candA[atomicAdd(&sh_cnt, 1)] = u;
    }
  }
  __syncthreads();
  int n = sh_cnt;
  // rounds 2..4 on compacted candidates
  unsigned* src = candA;
  unsigned* dst = candB;
#pragma unroll
  for (int rd = 0; rd < 3; ++rd) {
    const int shift = 16 - rd * 8;
    hist[tid] = 0;
    __syncthreads();
    for (int j = tid; j < n; j += 256) atomicAdd(&hist[(src[j] >> shift) & 255u], 1);
    __syncthreads();
    select_bin(hist, k, w, lane, &sh_bin, &sh_k);
    if (tid == 1) sh_cnt = 0;
    __syncthreads();
    const unsigned bsel = (unsigned)sh_bin;
    prefix |= bsel << shift;
    k = sh_k;
    if (shift > 0) {
      for (int j = tid; j < n; j += 256) {
        unsigned u = src[j];
        if (((u >> shift) & 255u) == bsel) dst[atomicAdd(&sh_cnt, 1)] = u;
      }
      __syncthreads();
      n = sh_cnt;
      unsigned* tmp = src; src = dst; dst = tmp;
    }
  }
  // emit bitmask: bit j = (key_j >= kth), exact reference tie semantics
  const unsigned kth = prefix;
#pragma unroll
  for (int s4 = 0; s4 < 4; ++s4) {
    int j = s4 * 256 + w * 64 + lane;
    bool bit = (j < n0) && (rowk[j] >= kth);
    unsigned long long m = __ballot(bit);
    if (lane == 0) maskb[((size_t)h * S_LEN + t) * 16 + (s4 * 4 + w)] = m;
  }
}

// ---------------- flash-style MFMA attention with bitmask -------------------
__global__ __launch_bounds__(256) void attn_mfma(
    const ushort_t* __restrict__ Qbf, const ushort_t* __restrict__ Kbf,
    const ushort_t* __restrict__ Vbf, const unsigned long long* __restrict__ maskb,
    ushort_t* __restrict__ AO) {
  __shared__ char sm[41984];
  const int tid = threadIdx.x, w = tid >> 6, lane = tid & 63;
  const int lo = lane & 15, hi = lane >> 4;
  const int rt = blockIdx.x, h = blockIdx.y;
  const int kvh = h >> 2;
  const int qrow = rt * 64 + w * 16 + lo;
  const int t0 = rt * 64 + w * 16 + hi * 4;

  bf16x8 qf[4];
  const ushort_t* qp = Qbf + (size_t)qrow * HID + h * HD;
#pragma unroll
  for (int ks = 0; ks < 4; ++ks) qf[ks] = *(const bf16x8*)(qp + ks * 32 + hi * 8);

  float mrun[4], lrun[4];
  f32x4 o[8];
#pragma unroll
  for (int r = 0; r < 4; ++r) { mrun[r] = -1e30f; lrun[r] = 0.f; }
#pragma unroll
  for (int n = 0; n < 8; ++n) o[n] = f32x4{0.f, 0.f, 0.f, 0.f};

  const int ntiles = rt + 1;
  for (int jt = 0; jt < ntiles; ++jt) {
    const int j0 = jt * 64;
#pragma unroll
    for (int p = 0; p < 4; ++p) {
      int idx = p * 256 + tid;
      int r = idx >> 4, c = idx & 15;
      bf16x8 v = *(const bf16x8*)(Kbf + (size_t)(j0 + r) * KVW + kvh * HD + c * 8);
      *(bf16x8*)(sm + ((r * 256 + c * 16) ^ ((r & 7) << 4))) = v;
    }
#pragma unroll
    for (int p = 0; p < 4; ++p) {
      int idx = p * 256 + tid;
      int j = idx & 63, dc = idx >> 6;
      bf16x8 v = *(const bf16x8*)(Vbf + (size_t)(j0 + j) * KVW + kvh * HD + dc * 8);
#pragma unroll
      for (int i = 0; i < 8; ++i) {
        int d = dc * 8 + i;
        *(ushort_t*)(sm + 16384 + ((d * 128 + j * 2) ^ ((d & 7) << 4))) = (ushort_t)v[i];
      }
    }
    __syncthreads();
    f32x4 s[4];
#pragma unroll
    for (int nf = 0; nf < 4; ++nf) {
      f32x4 a = f32x4{0.f, 0.f, 0.f, 0.f};
#pragma unroll
      for (int ks = 0; ks < 4; ++ks) {
        int r = nf * 16 + lo;
        bf16x8 kfr = *(const bf16x8*)(sm + ((r * 256 + ks * 64 + hi * 16) ^ ((r & 7) << 4)));
        a = MFMA16(qf[ks], kfr, a);
      }
      s[nf] = a;
    }
    // per-row mask words for this 64-wide tile
    unsigned long long wbits[4];
#pragma unroll
    for (int r = 0; r < 4; ++r) {
      int t = t0 + r;
      wbits[r] = (t >= FETCH_MAX) ? maskb[((size_t)h * S_LEN + t) * 16 + jt] : ~0ull;
    }
    float pvv[4][4];
    float tmax[4] = {-1e30f, -1e30f, -1e30f, -1e30f};
#pragma unroll
    for (int nf = 0; nf < 4; ++nf) {
      int j = j0 + nf * 16 + lo;
#pragma unroll
      for (int r = 0; r < 4; ++r) {
        int t = t0 + r;
        bool ok = (j <= t) && ((wbits[r] >> (nf * 16 + lo)) & 1ull);
        float val = ok ? s[nf][r] * SCALE_C : -1e30f;
        pvv[nf][r] = val;
        tmax[r] = fmaxf(tmax[r], val);
      }
    }
#pragma unroll
    for (int r = 0; r < 4; ++r) {
      float m = tmax[r];
      m = fmaxf(m, __shfl_xor(m, 1));
      m = fmaxf(m, __shfl_xor(m, 2));
      m = fmaxf(m, __shfl_xor(m, 4));
      m = fmaxf(m, __shfl_xor(m, 8));
      tmax[r] = m;
    }
    float alpha[4];
#pragma unroll
    for (int r = 0; r < 4; ++r) {
      float mnew = fmaxf(mrun[r], tmax[r]);
      alpha[r] = __expf(mrun[r] - mnew);
      mrun[r] = mnew;
    }
    float lsum[4] = {0.f, 0.f, 0.f, 0.f};
#pragma unroll
    for (int nf = 0; nf < 4; ++nf)
#pragma unroll
      for (int r = 0; r < 4; ++r) {
        float v2 = pvv[nf][r];
        float p = (v2 > -1e29f) ? __expf(v2 - mrun[r]) : 0.f;
        pvv[nf][r] = p;
        lsum[r] += p;
      }
#pragma unroll
    for (int r = 0; r < 4; ++r) {
      float ls = lsum[r];
      ls += __shfl_xor(ls, 1);
      ls += __shfl_xor(ls, 2);
      ls += __shfl_xor(ls, 4);
      ls += __shfl_xor(ls, 8);
      lrun[r] = lrun[r] * alpha[r] + ls;
#pragma unroll
      for (int n = 0; n < 8; ++n) o[n][r] *= alpha[r];
    }
    char* pb = sm + 32768 + w * 2304;
#pragma unroll
    for (int nf = 0; nf < 4; ++nf)
#pragma unroll
      for (int r = 0; r < 4; ++r)
        *(ushort_t*)(pb + (hi * 4 + r) * 144 + (nf * 16 + lo) * 2) = f2bf(pvv[nf][r]);
#pragma unroll
    for (int ks = 0; ks < 2; ++ks) {
      bf16x8 pa = *(const bf16x8*)(pb + lo * 144 + ks * 64 + hi * 16);
#pragma unroll
      for (int df = 0; df < 8; ++df) {
        int d = df * 16 + lo;
        bf16x8 vb = *(const bf16x8*)(sm + 16384 + ((d * 128 + ks * 64 + hi * 16) ^ ((d & 7) << 4)));
        o[df] = MFMA16(pa, vb, o[df]);
      }
    }
    __syncthreads();
  }
#pragma unroll
  for (int r = 0; r < 4; ++r) {
    float inv = 1.0f / lrun[r];
    int t = t0 + r;
#pragma unroll
    for (int df = 0; df < 8; ++df)
      AO[(size_t)t * HID + h * HD + df * 16 + lo] = f2bf(o[df][r] * inv);
  }
}

extern "C" void kernel_launch(void* const* d_in, const int* in_sizes, int n_in,
                              void* d_out, int out_size, void* d_ws, size_t ws_size,
                              hipStream_t stream) {
  const float* hidden = (const float*)d_in[0];
  const float* prev   = (const float*)d_in[1];
  const float* cosb   = (const float*)d_in[2];
  const float* sinb   = (const float*)d_in[3];
  const float* Wq     = (const float*)d_in[4];
  const float* Wk     = (const float*)d_in[5];
  const float* Wv     = (const float*)d_in[6];
  const float* Wo     = (const float*)d_in[7];
  float* out = (float*)d_out;

  char* ws = (char*)d_ws;
  const size_t MB = 1u << 20;
  float*    spec = (float*)(ws + 0);
  ushort_t* phi  = (ushort_t*)(ws + 0);
  ushort_t* plo  = (ushort_t*)(ws + 4 * MB);
  ushort_t* wqhi = (ushort_t*)(ws + 8 * MB);
  ushort_t* wqlo = (ushort_t*)(ws + 16 * MB);
  ushort_t* wkhi = (ushort_t*)(ws + 24 * MB);
  ushort_t* wklo = (ushort_t*)(ws + 26 * MB);
  ushort_t* hhi  = (ushort_t*)(ws + 64 * MB);
  ushort_t* hlo  = (ushort_t*)(ws + 68 * MB);
  ushort_t* qbf  = (ushort_t*)(ws + 72 * MB);
  ushort_t* qshi = (ushort_t*)(ws + 76 * MB);
  ushort_t* qslo = (ushort_t*)(ws + 80 * MB);
  ushort_t* khi  = (ushort_t*)(ws + 84 * MB);
  ushort_t* klo  = (ushort_t*)(ws + 85 * MB);
  ushort_t* vbf  = (ushort_t*)(ws + 86 * MB);
  ushort_t* wvbf = (ushort_t*)(ws + 87 * MB);
  int*   cnt = (int*)  (ws + 89 * MB);
  int*   fn  = (int*)  (ws + 89 * MB + (64u << 10));
  unsigned long long* maskb = (unsigned long long*)(ws + 90 * MB);  // 2MB
  ushort_t* wobf = (ushort_t*)(ws + 76 * MB);
  ushort_t* aobf = (ushort_t*)(ws + 64 * MB);

  // conversions
  to_bf16_split<<<1024, 256, 0, stream>>>(hidden, hhi, hlo, S_LEN * HID);
  to_bf16_split<<<1024, 256, 0, stream>>>(prev, phi, plo, S_LEN * HID);
  to_bf16_split<<<2048, 256, 0, stream>>>(Wq, wqhi, wqlo, HID * HID);
  to_bf16_split<<<512, 256, 0, stream>>>(Wk, wkhi, wklo, KVW * HID);
  to_bf16<<<512, 256, 0, stream>>>(Wv, wvbf, KVW * HID);

  // projections
  proj_gemm<<<dim3(16, 8), 256, 0, stream>>>(hhi, wqhi, qbf, cosb, sinb, HID, 1);
  proj3_gemm<<<dim3(16, 8), 256, 0, stream>>>(phi, plo, wqhi, wqlo, qshi, qslo, cosb, sinb, HID);
  proj3_gemm<<<dim3(4, 8), 256, 0, stream>>>(hhi, hlo, wkhi, wklo, khi, klo, cosb, sinb, KVW);
  proj_gemm<<<dim3(4, 8), 256, 0, stream>>>(hhi, wvbf, vbf, cosb, sinb, KVW, 0);

  // speculative scores (fp32-accurate)
  spec3_gemm<<<dim3(8, 8, NHEADS), 256, 0, stream>>>(qshi, qslo, khi, klo, spec);

  // mask statistics (exact on fp32 spec)
  count_kernel<<<dim3(S_LEN - FETCH_MAX, NHEADS), 256, 0, stream>>>(spec, cnt);
  fn_kernel<<<(S_LEN - FETCH_MAX + 255) / 256, 256, 0, stream>>>(cnt, fn);
  thr_kernel<<<dim3(S_LEN - FETCH_MAX, NHEADS), 256, 0, stream>>>(spec, fn, maskb);

  // Wo conversion into region freed after spec3 (qshi/qslo dead)
  to_bf16<<<2048, 256, 0, stream>>>(Wo, wobf, HID * HID);

  // attention (bitmask-driven)
  attn_mfma<<<dim3(16, NHEADS), 256, 0, stream>>>(qbf, khi, vbf, maskb, aobf);

  // output projection
  out_gemm<<<dim3(16, 8), 256, 0, stream>>>(aobf, wobf, out);
}

// Round 5
// 300.084 us; speedup vs baseline: 6.5338x; 1.3488x over previous
//
#include <hip/hip_runtime.h>
#include <hip/hip_bf16.h>

#define S_LEN 1024
#define HID 2048
#define NHEADS 16
#define KVHEADS 4
#define HD 128
#define KVW 512
#define FETCH_MAX 204
#define ALPHA_C 5.0f
#define SCALE_C 0.08838834764831845f

typedef __attribute__((ext_vector_type(8))) short bf16x8;
typedef __attribute__((ext_vector_type(4))) float f32x4;
typedef unsigned short ushort_t;

#define MFMA16(a, b, c) __builtin_amdgcn_mfma_f32_16x16x32_bf16(a, b, c, 0, 0, 0)

__device__ __forceinline__ ushort_t f2bf(float f) {
  unsigned u = __float_as_uint(f);
  return (ushort_t)((u + 0x7fffu + ((u >> 16) & 1u)) >> 16);
}
__device__ __forceinline__ float bf2f(ushort_t h) {
  return __uint_as_float(((unsigned)h) << 16);
}

// ---------------- fp32 -> bf16, 8 elems/thread ------------------------------
__global__ __launch_bounds__(256) void to_bf16(const float* __restrict__ in,
                                               ushort_t* __restrict__ out, int n) {
  int i = (blockIdx.x * 256 + threadIdx.x) * 8;
  if (i >= n) return;
  float4 a = *(const float4*)(in + i);
  float4 b = *(const float4*)(in + i + 4);
  bf16x8 v;
  v[0] = (short)f2bf(a.x); v[1] = (short)f2bf(a.y);
  v[2] = (short)f2bf(a.z); v[3] = (short)f2bf(a.w);
  v[4] = (short)f2bf(b.x); v[5] = (short)f2bf(b.y);
  v[6] = (short)f2bf(b.z); v[7] = (short)f2bf(b.w);
  *(bf16x8*)(out + i) = v;
}

// ---------------- fp32 -> bf16 hi/lo split, 8 elems/thread ------------------
__global__ __launch_bounds__(256) void to_bf16_split(const float* __restrict__ in,
                                                     ushort_t* __restrict__ hi,
                                                     ushort_t* __restrict__ lo, int n) {
  int i = (blockIdx.x * 256 + threadIdx.x) * 8;
  if (i >= n) return;
  bf16x8 vh, vl;
#pragma unroll
  for (int q = 0; q < 8; ++q) {
    float x = in[i + q];
    ushort_t h = f2bf(x);
    vh[q] = (short)h;
    vl[q] = (short)f2bf(x - bf2f(h));
  }
  *(bf16x8*)(hi + i) = vh;
  *(bf16x8*)(lo + i) = vl;
}

// ============ merged 3-pass projections (Qs and K), BM=64 BN=128 BK=64 ======
// 8 waves: wave w owns rows (w&3)*16..+15, col frags {npar, npar+2, npar+4,
// npar+6} (npar = w>>2) so RoPE pairs (nf, nf+4) stay wave-local.
__global__ __launch_bounds__(512) void proj3_all(
    const ushort_t* __restrict__ Aq_h, const ushort_t* __restrict__ Aq_l,
    const ushort_t* __restrict__ Ak_h, const ushort_t* __restrict__ Ak_l,
    const ushort_t* __restrict__ Wq_h, const ushort_t* __restrict__ Wq_l,
    const ushort_t* __restrict__ Wk_h, const ushort_t* __restrict__ Wk_l,
    ushort_t* __restrict__ Oq_h, ushort_t* __restrict__ Oq_l,
    ushort_t* __restrict__ Ok_h, ushort_t* __restrict__ Ok_l,
    const float* __restrict__ cosb, const float* __restrict__ sinb) {
  __shared__ char sm[49152];
  char* Ah = sm;
  char* Al = sm + 8192;
  char* Bh = sm + 16384;
  char* Bl = sm + 32768;
  const int tid = threadIdx.x, w = tid >> 6, lane = tid & 63;
  const int lo = lane & 15, hi = lane >> 4;
  const int bid = blockIdx.x;
  const ushort_t *Ahi, *Alo, *Whi, *Wlo;
  ushort_t *Ohi, *Olo;
  int N, bm, bn;
  if (bid < 256) {
    bm = (bid >> 4) * 64; bn = (bid & 15) * 128; N = HID;
    Ahi = Aq_h; Alo = Aq_l; Whi = Wq_h; Wlo = Wq_l; Ohi = Oq_h; Olo = Oq_l;
  } else {
    int i = bid - 256;
    bm = (i >> 2) * 64; bn = (i & 3) * 128; N = KVW;
    Ahi = Ak_h; Alo = Ak_l; Whi = Wk_h; Wlo = Wk_l; Ohi = Ok_h; Olo = Ok_l;
  }
  const int mrow = (w & 3) * 16, npar = w >> 2;
  f32x4 acc[4];
#pragma unroll
  for (int i = 0; i < 4; ++i) acc[i] = f32x4{0.f, 0.f, 0.f, 0.f};

  for (int k0 = 0; k0 < HID; k0 += 64) {
    {
      int r = tid >> 3, c = tid & 7;
      size_t ga = (size_t)(bm + r) * HID + k0 + c * 8;
      int off = (r * 128 + c * 16) ^ ((r & 7) << 4);
      *(bf16x8*)(Ah + off) = *(const bf16x8*)(Ahi + ga);
      *(bf16x8*)(Al + off) = *(const bf16x8*)(Alo + ga);
    }
#pragma unroll
    for (int p = 0; p < 2; ++p) {
      int idx = p * 512 + tid;
      int r = idx >> 3, c = idx & 7;
      size_t gb = (size_t)(bn + r) * HID + k0 + c * 8;
      int off = (r * 128 + c * 16) ^ ((r & 7) << 4);
      *(bf16x8*)(Bh + off) = *(const bf16x8*)(Whi + gb);
      *(bf16x8*)(Bl + off) = *(const bf16x8*)(Wlo + gb);
    }
    __syncthreads();
#pragma unroll
    for (int ks = 0; ks < 2; ++ks) {
      const int ko = ks * 64 + hi * 16;
      const int ar = mrow + lo;
      const int aoff = (ar * 128 + ko) ^ ((ar & 7) << 4);
      bf16x8 ah = *(const bf16x8*)(Ah + aoff);
      bf16x8 al = *(const bf16x8*)(Al + aoff);
#pragma unroll
      for (int i = 0; i < 4; ++i) {
        int br = (npar + 2 * i) * 16 + lo;
        int boff = (br * 128 + ko) ^ ((br & 7) << 4);
        bf16x8 bh = *(const bf16x8*)(Bh + boff);
        bf16x8 bl = *(const bf16x8*)(Bl + boff);
        acc[i] = MFMA16(ah, bh, acc[i]);
        acc[i] = MFMA16(ah, bl, acc[i]);
        acc[i] = MFMA16(al, bh, acc[i]);
      }
    }
    __syncthreads();
  }
  // fp32 RoPE epilogue, re-split hi/lo; pairs: acc[i] (col d) & acc[i+2] (d+64)
#pragma unroll
  for (int i = 0; i < 2; ++i)
#pragma unroll
    for (int r = 0; r < 4; ++r) {
      int t = bm + mrow + hi * 4 + r;
      int d = (npar + 2 * i) * 16 + lo;           // < 64
      float x1 = acc[i][r], x2 = acc[i + 2][r];
      float c1 = cosb[t * HD + d], s1 = sinb[t * HD + d];
      float c2 = cosb[t * HD + d + 64], s2 = sinb[t * HD + d + 64];
      float y1 = x1 * c1 - x2 * s1;
      float y2 = x2 * c2 + x1 * s2;
      ushort_t h1 = f2bf(y1), h2 = f2bf(y2);
      size_t o1 = (size_t)t * N + bn + d;
      size_t o2 = o1 + 64;
      Ohi[o1] = h1; Olo[o1] = f2bf(y1 - bf2f(h1));
      Ohi[o2] = h2; Olo[o2] = f2bf(y2 - bf2f(h2));
    }
}

// ============ merged 1-pass projections (Q rope, V plain), BM=64 BN=128 =====
__global__ __launch_bounds__(512) void proj1_all(
    const ushort_t* __restrict__ Abf, const ushort_t* __restrict__ Wq,
    const ushort_t* __restrict__ Wv, ushort_t* __restrict__ Oq,
    ushort_t* __restrict__ Ov, const float* __restrict__ cosb,
    const float* __restrict__ sinb) {
  __shared__ char sm[24576];
  char* As = sm;
  char* Bs = sm + 8192;
  const int tid = threadIdx.x, w = tid >> 6, lane = tid & 63;
  const int lo = lane & 15, hi = lane >> 4;
  const int bid = blockIdx.x;
  const ushort_t* Wmat;
  ushort_t* Out;
  int N, bm, bn, do_rope;
  if (bid < 256) {
    bm = (bid >> 4) * 64; bn = (bid & 15) * 128; N = HID;
    Wmat = Wq; Out = Oq; do_rope = 1;
  } else {
    int i = bid - 256;
    bm = (i >> 2) * 64; bn = (i & 3) * 128; N = KVW;
    Wmat = Wv; Out = Ov; do_rope = 0;
  }
  const int mrow = (w & 3) * 16, npar = w >> 2;
  f32x4 acc[4];
#pragma unroll
  for (int i = 0; i < 4; ++i) acc[i] = f32x4{0.f, 0.f, 0.f, 0.f};

  for (int k0 = 0; k0 < HID; k0 += 64) {
    {
      int r = tid >> 3, c = tid & 7;
      *(bf16x8*)(As + ((r * 128 + c * 16) ^ ((r & 7) << 4))) =
          *(const bf16x8*)(Abf + (size_t)(bm + r) * HID + k0 + c * 8);
    }
#pragma unroll
    for (int p = 0; p < 2; ++p) {
      int idx = p * 512 + tid;
      int r = idx >> 3, c = idx & 7;
      *(bf16x8*)(Bs + ((r * 128 + c * 16) ^ ((r & 7) << 4))) =
          *(const bf16x8*)(Wmat + (size_t)(bn + r) * HID + k0 + c * 8);
    }
    __syncthreads();
#pragma unroll
    for (int ks = 0; ks < 2; ++ks) {
      const int ko = ks * 64 + hi * 16;
      const int ar = mrow + lo;
      bf16x8 af = *(const bf16x8*)(As + ((ar * 128 + ko) ^ ((ar & 7) << 4)));
#pragma unroll
      for (int i = 0; i < 4; ++i) {
        int br = (npar + 2 * i) * 16 + lo;
        bf16x8 bf = *(const bf16x8*)(Bs + ((br * 128 + ko) ^ ((br & 7) << 4)));
        acc[i] = MFMA16(af, bf, acc[i]);
      }
    }
    __syncthreads();
  }
#pragma unroll
  for (int i = 0; i < 2; ++i)
#pragma unroll
    for (int r = 0; r < 4; ++r) {
      int t = bm + mrow + hi * 4 + r;
      int d = (npar + 2 * i) * 16 + lo;
      float x1 = acc[i][r], x2 = acc[i + 2][r];
      float y1, y2;
      if (do_rope) {
        float c1 = cosb[t * HD + d], s1 = sinb[t * HD + d];
        float c2 = cosb[t * HD + d + 64], s2 = sinb[t * HD + d + 64];
        y1 = x1 * c1 - x2 * s1;
        y2 = x2 * c2 + x1 * s2;
      } else {
        y1 = x1; y2 = x2;
      }
      Out[(size_t)t * N + bn + d] = f2bf(y1);
      Out[(size_t)t * N + bn + d + 64] = f2bf(y2);
    }
}

// ---------------- 3-pass spec GEMM, causal tiles only -----------------------
__global__ __launch_bounds__(256) void spec3_gemm(
    const ushort_t* __restrict__ Qhi, const ushort_t* __restrict__ Qlo,
    const ushort_t* __restrict__ Khi, const ushort_t* __restrict__ Klo,
    float* __restrict__ spec) {
  __shared__ char sm[65536];
  char* Ah = sm;
  char* Al = sm + 16384;
  char* Bh = sm + 32768;
  char* Bl = sm + 49152;
  const int tid = threadIdx.x, w = tid >> 6, lane = tid & 63;
  const int lo = lane & 15, hi = lane >> 4;
  const int bid = blockIdx.x;
  const int h = bid / 36;
  int tl = bid % 36;
  int mi = 0;
#pragma unroll
  for (int m = 1; m < 8; ++m) if ((m * (m + 1)) / 2 <= tl) mi = m;
  const int ni = tl - (mi * (mi + 1)) / 2;
  const int bm = mi * 128, bn = ni * 128;
  const ushort_t* Abh = Qhi + h * HD;
  const ushort_t* Abl = Qlo + h * HD;
  const ushort_t* Bbh = Khi + (h >> 2) * HD;
  const ushort_t* Bbl = Klo + (h >> 2) * HD;
  float* C = spec + (size_t)h * S_LEN * S_LEN;
  f32x4 acc[2][8];
#pragma unroll
  for (int m = 0; m < 2; ++m)
#pragma unroll
    for (int n = 0; n < 8; ++n) acc[m][n] = f32x4{0.f, 0.f, 0.f, 0.f};

  for (int k0 = 0; k0 < HD; k0 += 64) {
#pragma unroll
    for (int p = 0; p < 4; ++p) {
      int idx = p * 256 + tid;
      int r = idx >> 3, c = idx & 7;
      size_t ga = (size_t)(bm + r) * HID + k0 + c * 8;
      size_t gb = (size_t)(bn + r) * KVW + k0 + c * 8;
      int off = (r * 128 + c * 16) ^ ((r & 7) << 4);
      *(bf16x8*)(Ah + off) = *(const bf16x8*)(Abh + ga);
      *(bf16x8*)(Al + off) = *(const bf16x8*)(Abl + ga);
      *(bf16x8*)(Bh + off) = *(const bf16x8*)(Bbh + gb);
      *(bf16x8*)(Bl + off) = *(const bf16x8*)(Bbl + gb);
    }
    __syncthreads();
#pragma unroll
    for (int ks = 0; ks < 2; ++ks) {
      const int ko = ks * 64 + hi * 16;
      bf16x8 ah[2], al[2];
#pragma unroll
      for (int m = 0; m < 2; ++m) {
        int r = w * 32 + m * 16 + lo;
        int off = (r * 128 + ko) ^ ((r & 7) << 4);
        ah[m] = *(const bf16x8*)(Ah + off);
        al[m] = *(const bf16x8*)(Al + off);
      }
#pragma unroll
      for (int n = 0; n < 8; ++n) {
        int r = n * 16 + lo;
        int off = (r * 128 + ko) ^ ((r & 7) << 4);
        bf16x8 bh = *(const bf16x8*)(Bh + off);
        bf16x8 bl = *(const bf16x8*)(Bl + off);
#pragma unroll
        for (int m = 0; m < 2; ++m) {
          acc[m][n] = MFMA16(ah[m], bh, acc[m][n]);
          acc[m][n] = MFMA16(ah[m], bl, acc[m][n]);
          acc[m][n] = MFMA16(al[m], bh, acc[m][n]);
        }
      }
    }
    __syncthreads();
  }
#pragma unroll
  for (int m = 0; m < 2; ++m)
#pragma unroll
    for (int nf = 0; nf < 8; ++nf)
#pragma unroll
      for (int r = 0; r < 4; ++r) {
        int t = bm + w * 32 + m * 16 + hi * 4 + r;
        int j = bn + nf * 16 + lo;
        C[(size_t)t * S_LEN + j] = acc[m][nf][r] * SCALE_C;
      }
}

// ---------------- output GEMM: out = AO @ Wo^T, BM=64 BN=128 ----------------
__global__ __launch_bounds__(512) void out_gemm(
    const ushort_t* __restrict__ A, const ushort_t* __restrict__ W,
    float* __restrict__ Out) {
  __shared__ char sm[24576];
  char* As = sm;
  char* Bs = sm + 8192;
  const int tid = threadIdx.x, w = tid >> 6, lane = tid & 63;
  const int lo = lane & 15, hi = lane >> 4;
  const int bm = blockIdx.y * 64, bn = blockIdx.x * 128;
  const int mrow = (w & 3) * 16, npar = w >> 2;
  f32x4 acc[4];
#pragma unroll
  for (int i = 0; i < 4; ++i) acc[i] = f32x4{0.f, 0.f, 0.f, 0.f};

  for (int k0 = 0; k0 < HID; k0 += 64) {
    {
      int r = tid >> 3, c = tid & 7;
      *(bf16x8*)(As + ((r * 128 + c * 16) ^ ((r & 7) << 4))) =
          *(const bf16x8*)(A + (size_t)(bm + r) * HID + k0 + c * 8);
    }
#pragma unroll
    for (int p = 0; p < 2; ++p) {
      int idx = p * 512 + tid;
      int r = idx >> 3, c = idx & 7;
      *(bf16x8*)(Bs + ((r * 128 + c * 16) ^ ((r & 7) << 4))) =
          *(const bf16x8*)(W + (size_t)(bn + r) * HID + k0 + c * 8);
    }
    __syncthreads();
#pragma unroll
    for (int ks = 0; ks < 2; ++ks) {
      const int ko = ks * 64 + hi * 16;
      const int ar = mrow + lo;
      bf16x8 af = *(const bf16x8*)(As + ((ar * 128 + ko) ^ ((ar & 7) << 4)));
#pragma unroll
      for (int i = 0; i < 4; ++i) {
        int br = (npar + 2 * i) * 16 + lo;
        bf16x8 bf = *(const bf16x8*)(Bs + ((br * 128 + ko) ^ ((br & 7) << 4)));
        acc[i] = MFMA16(af, bf, acc[i]);
      }
    }
    __syncthreads();
  }
#pragma unroll
  for (int i = 0; i < 4; ++i)
#pragma unroll
    for (int r = 0; r < 4; ++r) {
      int t = bm + mrow + hi * 4 + r;
      Out[(size_t)t * HID + bn + (npar + 2 * i) * 16 + lo] = acc[i][r];
    }
}

// ---------------- per-(h,t>=204): rowmax + count(>= max-ALPHA), LDS-cached --
__global__ __launch_bounds__(256) void count_kernel(
    const float* __restrict__ spec, int* __restrict__ cnt) {
  const int t = blockIdx.x + FETCH_MAX, h = blockIdx.y, tid = threadIdx.x;
  const int w = tid >> 6, lane = tid & 63;
  __shared__ float rowc[1024];
  __shared__ float wmax[4];
  __shared__ int wcnt[4];
  const float* row = spec + ((size_t)h * S_LEN + t) * S_LEN;
  float mx = -1e30f;
  for (int j = tid; j <= t; j += 256) {
    float v = row[j];
    rowc[j] = v;
    mx = fmaxf(mx, v);
  }
#pragma unroll
  for (int d = 1; d < 64; d <<= 1) mx = fmaxf(mx, __shfl_xor(mx, d));
  if (lane == 0) wmax[w] = mx;
  __syncthreads();
  const float cut = fmaxf(fmaxf(wmax[0], wmax[1]), fmaxf(wmax[2], wmax[3])) - ALPHA_C;
  int c = 0;
  for (int j = tid; j <= t; j += 256) c += (rowc[j] >= cut) ? 1 : 0;
#pragma unroll
  for (int d = 1; d < 64; d <<= 1) c += __shfl_xor(c, d);
  if (lane == 0) wcnt[w] = c;
  __syncthreads();
  if (tid == 0) cnt[h * S_LEN + t] = wcnt[0] + wcnt[1] + wcnt[2] + wcnt[3];
}

__global__ __launch_bounds__(256) void fn_kernel(
    const int* __restrict__ cnt, int* __restrict__ fn) {
  int t = FETCH_MAX + blockIdx.x * 256 + threadIdx.x;
  if (t >= S_LEN) return;
  int s = 0;
#pragma unroll
  for (int h = 0; h < NHEADS; ++h) s += cnt[h * S_LEN + t];
  int f = s >> 4;
  fn[t] = f > FETCH_MAX ? FETCH_MAX : f;
}

// ---- wave-0 parallel bin select: largest bin b with suffix-count >= k ------
__device__ __forceinline__ void select_bin(const int* hist, int k, int w, int lane,
                                           int* sh_bin, int* sh_k) {
  if (w == 0) {
    const int base = 252 - 4 * lane;
    int c0 = hist[base], c1 = hist[base + 1], c2 = hist[base + 2], c3 = hist[base + 3];
    int s = c0 + c1 + c2 + c3;
    int p = s;
#pragma unroll
    for (int d = 1; d < 64; d <<= 1) {
      int q = __shfl_up(p, d);
      if (lane >= d) p += q;
    }
    unsigned long long m = __ballot(p >= k);
    int lsel = __ffsll((unsigned long long)m) - 1;
    if (lane == lsel) {
      int cum = p - s;
      int b;
      if (cum + c3 >= k) { b = base + 3; }
      else if (cum + c3 + c2 >= k) { cum += c3; b = base + 2; }
      else if (cum + c3 + c2 + c1 >= k) { cum += c3 + c2; b = base + 1; }
      else { cum += c3 + c2 + c1; b = base; }
      *sh_bin = b;
      *sh_k = k - cum;
    }
  }
}

// ---------------- exact k-th largest -> bitmask, LDS-cached radix select ----
__global__ __launch_bounds__(256) void thr_kernel(
    const float* __restrict__ spec, const int* __restrict__ fn,
    unsigned long long* __restrict__ maskb) {
  const int t = blockIdx.x + FETCH_MAX, h = blockIdx.y;
  const int tid = threadIdx.x, w = tid >> 6, lane = tid & 63;
  __shared__ unsigned rowk[1024];
  __shared__ unsigned candA[1024];
  __shared__ unsigned candB[1024];
  __shared__ int hist4[4][256];
  __shared__ int hist[256];
  __shared__ int sh_bin, sh_k, sh_cnt;
  const float* row = spec + ((size_t)h * S_LEN + t) * S_LEN;
  const int n0 = t + 1;
  int k = fn[t];
  hist4[0][tid] = 0; hist4[1][tid] = 0; hist4[2][tid] = 0; hist4[3][tid] = 0;
  if (tid == 0) sh_cnt = 0;
  __syncthreads();
  for (int j = tid; j < n0; j += 256) {
    unsigned bits = __float_as_uint(row[j]);
    unsigned u = (bits & 0x80000000u) ? ~bits : (bits | 0x80000000u);
    rowk[j] = u;
    atomicAdd(&hist4[w][u >> 24], 1);
  }
  __syncthreads();
  hist[tid] = hist4[0][tid] + hist4[1][tid] + hist4[2][tid] + hist4[3][tid];
  __syncthreads();
  select_bin(hist, k, w, lane, &sh_bin, &sh_k);
  __syncthreads();
  unsigned prefix = (unsigned)sh_bin << 24;
  k = sh_k;
  {
    const unsigned bsel = (unsigned)sh_bin;
    for (int j = tid; j < n0; j += 256) {
      unsigned u = rowk[j];
      if ((u >> 24) == bsel) candA[atomicAdd(&sh_cnt, 1)] = u;
    }
  }
  __syncthreads();
  int n = sh_cnt;
  unsigned* src = candA;
  unsigned* dst = candB;
#pragma unroll
  for (int rd = 0; rd < 3; ++rd) {
    const int shift = 16 - rd * 8;
    hist[tid] = 0;
    __syncthreads();
    for (int j = tid; j < n; j += 256) atomicAdd(&hist[(src[j] >> shift) & 255u], 1);
    __syncthreads();
    select_bin(hist, k, w, lane, &sh_bin, &sh_k);
    if (tid == 1) sh_cnt = 0;
    __syncthreads();
    const unsigned bsel = (unsigned)sh_bin;
    prefix |= bsel << shift;
    k = sh_k;
    if (shift > 0) {
      for (int j = tid; j < n; j += 256) {
        unsigned u = src[j];
        if (((u >> shift) & 255u) == bsel) dst[atomicAdd(&sh_cnt, 1)] = u;
      }
      __syncthreads();
      n = sh_cnt;
      unsigned* tmp = src; src = dst; dst = tmp;
    }
  }
  const unsigned kth = prefix;
#pragma unroll
  for (int s4 = 0; s4 < 4; ++s4) {
    int j = s4 * 256 + w * 64 + lane;
    bool bit = (j < n0) && (rowk[j] >= kth);
    unsigned long long m = __ballot(bit);
    if (lane == 0) maskb[((size_t)h * S_LEN + t) * 16 + (s4 * 4 + w)] = m;
  }
}

// ---------------- flash-style MFMA attention with bitmask -------------------
__global__ __launch_bounds__(256) void attn_mfma(
    const ushort_t* __restrict__ Qbf, const ushort_t* __restrict__ Kbf,
    const ushort_t* __restrict__ Vbf, const unsigned long long* __restrict__ maskb,
    ushort_t* __restrict__ AO) {
  __shared__ char sm[41984];
  const int tid = threadIdx.x, w = tid >> 6, lane = tid & 63;
  const int lo = lane & 15, hi = lane >> 4;
  const int rt = blockIdx.x, h = blockIdx.y;
  const int kvh = h >> 2;
  const int qrow = rt * 64 + w * 16 + lo;
  const int t0 = rt * 64 + w * 16 + hi * 4;

  bf16x8 qf[4];
  const ushort_t* qp = Qbf + (size_t)qrow * HID + h * HD;
#pragma unroll
  for (int ks = 0; ks < 4; ++ks) qf[ks] = *(const bf16x8*)(qp + ks * 32 + hi * 8);

  float mrun[4], lrun[4];
  f32x4 o[8];
#pragma unroll
  for (int r = 0; r < 4; ++r) { mrun[r] = -1e30f; lrun[r] = 0.f; }
#pragma unroll
  for (int n = 0; n < 8; ++n) o[n] = f32x4{0.f, 0.f, 0.f, 0.f};

  const int ntiles = rt + 1;
  for (int jt = 0; jt < ntiles; ++jt) {
    const int j0 = jt * 64;
#pragma unroll
    for (int p = 0; p < 4; ++p) {
      int idx = p * 256 + tid;
      int r = idx >> 4, c = idx & 15;
      bf16x8 v = *(const bf16x8*)(Kbf + (size_t)(j0 + r) * KVW + kvh * HD + c * 8);
      *(bf16x8*)(sm + ((r * 256 + c * 16) ^ ((r & 7) << 4))) = v;
    }
#pragma unroll
    for (int p = 0; p < 4; ++p) {
      int idx = p * 256 + tid;
      int j = idx & 63, dc = idx >> 6;
      bf16x8 v = *(const bf16x8*)(Vbf + (size_t)(j0 + j) * KVW + kvh * HD + dc * 8);
#pragma unroll
      for (int i = 0; i < 8; ++i) {
        int d = dc * 8 + i;
        *(ushort_t*)(sm + 16384 + ((d * 128 + j * 2) ^ ((d & 7) << 4))) = (ushort_t)v[i];
      }
    }
    __syncthreads();
    f32x4 s[4];
#pragma unroll
    for (int nf = 0; nf < 4; ++nf) {
      f32x4 a = f32x4{0.f, 0.f, 0.f, 0.f};
#pragma unroll
      for (int ks = 0; ks < 4; ++ks) {
        int r = nf * 16 + lo;
        bf16x8 kfr = *(const bf16x8*)(sm + ((r * 256 + ks * 64 + hi * 16) ^ ((r & 7) << 4)));
        a = MFMA16(qf[ks], kfr, a);
      }
      s[nf] = a;
    }
    unsigned long long wbits[4];
#pragma unroll
    for (int r = 0; r < 4; ++r) {
      int t = t0 + r;
      wbits[r] = (t >= FETCH_MAX) ? maskb[((size_t)h * S_LEN + t) * 16 + jt] : ~0ull;
    }
    float pvv[4][4];
    float tmax[4] = {-1e30f, -1e30f, -1e30f, -1e30f};
#pragma unroll
    for (int nf = 0; nf < 4; ++nf) {
      int j = j0 + nf * 16 + lo;
#pragma unroll
      for (int r = 0; r < 4; ++r) {
        int t = t0 + r;
        bool ok = (j <= t) && ((wbits[r] >> (nf * 16 + lo)) & 1ull);
        float val = ok ? s[nf][r] * SCALE_C : -1e30f;
        pvv[nf][r] = val;
        tmax[r] = fmaxf(tmax[r], val);
      }
    }
#pragma unroll
    for (int r = 0; r < 4; ++r) {
      float m = tmax[r];
      m = fmaxf(m, __shfl_xor(m, 1));
      m = fmaxf(m, __shfl_xor(m, 2));
      m = fmaxf(m, __shfl_xor(m, 4));
      m = fmaxf(m, __shfl_xor(m, 8));
      tmax[r] = m;
    }
    float alpha[4];
#pragma unroll
    for (int r = 0; r < 4; ++r) {
      float mnew = fmaxf(mrun[r], tmax[r]);
      alpha[r] = __expf(mrun[r] - mnew);
      mrun[r] = mnew;
    }
    float lsum[4] = {0.f, 0.f, 0.f, 0.f};
#pragma unroll
    for (int nf = 0; nf < 4; ++nf)
#pragma unroll
      for (int r = 0; r < 4; ++r) {
        float v2 = pvv[nf][r];
        float p = (v2 > -1e29f) ? __expf(v2 - mrun[r]) : 0.f;
        pvv[nf][r] = p;
        lsum[r] += p;
      }
#pragma unroll
    for (int r = 0; r < 4; ++r) {
      float ls = lsum[r];
      ls += __shfl_xor(ls, 1);
      ls += __shfl_xor(ls, 2);
      ls += __shfl_xor(ls, 4);
      ls += __shfl_xor(ls, 8);
      lrun[r] = lrun[r] * alpha[r] + ls;
#pragma unroll
      for (int n = 0; n < 8; ++n) o[n][r] *= alpha[r];
    }
    char* pb = sm + 32768 + w * 2304;
#pragma unroll
    for (int nf = 0; nf < 4; ++nf)
#pragma unroll
      for (int r = 0; r < 4; ++r)
        *(ushort_t*)(pb + (hi * 4 + r) * 144 + (nf * 16 + lo) * 2) = f2bf(pvv[nf][r]);
#pragma unroll
    for (int ks = 0; ks < 2; ++ks) {
      bf16x8 pa = *(const bf16x8*)(pb + lo * 144 + ks * 64 + hi * 16);
#pragma unroll
      for (int df = 0; df < 8; ++df) {
        int d = df * 16 + lo;
        bf16x8 vb = *(const bf16x8*)(sm + 16384 + ((d * 128 + ks * 64 + hi * 16) ^ ((d & 7) << 4)));
        o[df] = MFMA16(pa, vb, o[df]);
      }
    }
    __syncthreads();
  }
#pragma unroll
  for (int r = 0; r < 4; ++r) {
    float inv = 1.0f / lrun[r];
    int t = t0 + r;
#pragma unroll
    for (int df = 0; df < 8; ++df)
      AO[(size_t)t * HID + h * HD + df * 16 + lo] = f2bf(o[df][r] * inv);
  }
}

extern "C" void kernel_launch(void* const* d_in, const int* in_sizes, int n_in,
                              void* d_out, int out_size, void* d_ws, size_t ws_size,
                              hipStream_t stream) {
  const float* hidden = (const float*)d_in[0];
  const float* prev   = (const float*)d_in[1];
  const float* cosb   = (const float*)d_in[2];
  const float* sinb   = (const float*)d_in[3];
  const float* Wq     = (const float*)d_in[4];
  const float* Wk     = (const float*)d_in[5];
  const float* Wv     = (const float*)d_in[6];
  const float* Wo     = (const float*)d_in[7];
  float* out = (float*)d_out;

  char* ws = (char*)d_ws;
  const size_t MB = 1u << 20;
  float*    spec = (float*)(ws + 0);
  ushort_t* phi  = (ushort_t*)(ws + 0);
  ushort_t* plo  = (ushort_t*)(ws + 4 * MB);
  ushort_t* wqhi = (ushort_t*)(ws + 8 * MB);
  ushort_t* wqlo = (ushort_t*)(ws + 16 * MB);
  ushort_t* wkhi = (ushort_t*)(ws + 24 * MB);
  ushort_t* wklo = (ushort_t*)(ws + 26 * MB);
  ushort_t* hhi  = (ushort_t*)(ws + 64 * MB);
  ushort_t* hlo  = (ushort_t*)(ws + 68 * MB);
  ushort_t* qbf  = (ushort_t*)(ws + 72 * MB);
  ushort_t* qshi = (ushort_t*)(ws + 76 * MB);
  ushort_t* qslo = (ushort_t*)(ws + 80 * MB);
  ushort_t* khi  = (ushort_t*)(ws + 84 * MB);
  ushort_t* klo  = (ushort_t*)(ws + 85 * MB);
  ushort_t* vbf  = (ushort_t*)(ws + 86 * MB);
  ushort_t* wvbf = (ushort_t*)(ws + 87 * MB);
  int*   cnt = (int*)  (ws + 89 * MB);
  int*   fn  = (int*)  (ws + 89 * MB + (64u << 10));
  unsigned long long* maskb = (unsigned long long*)(ws + 90 * MB);  // 2MB
  ushort_t* wobf = (ushort_t*)(ws + 76 * MB);
  ushort_t* aobf = (ushort_t*)(ws + 64 * MB);

  // conversions
  to_bf16_split<<<1024, 256, 0, stream>>>(hidden, hhi, hlo, S_LEN * HID);
  to_bf16_split<<<1024, 256, 0, stream>>>(prev, phi, plo, S_LEN * HID);
  to_bf16_split<<<2048, 256, 0, stream>>>(Wq, wqhi, wqlo, HID * HID);
  to_bf16_split<<<512, 256, 0, stream>>>(Wk, wkhi, wklo, KVW * HID);
  to_bf16<<<512, 256, 0, stream>>>(Wv, wvbf, KVW * HID);

  // merged projections
  proj3_all<<<320, 512, 0, stream>>>(phi, plo, hhi, hlo, wqhi, wqlo, wkhi, wklo,
                                     qshi, qslo, khi, klo, cosb, sinb);
  proj1_all<<<320, 512, 0, stream>>>(hhi, wqhi, wvbf, qbf, vbf, cosb, sinb);

  // speculative scores (fp32-accurate, causal tiles only)
  spec3_gemm<<<576, 256, 0, stream>>>(qshi, qslo, khi, klo, spec);

  // mask statistics (exact on fp32 spec)
  count_kernel<<<dim3(S_LEN - FETCH_MAX, NHEADS), 256, 0, stream>>>(spec, cnt);
  fn_kernel<<<(S_LEN - FETCH_MAX + 255) / 256, 256, 0, stream>>>(cnt, fn);
  thr_kernel<<<dim3(S_LEN - FETCH_MAX, NHEADS), 256, 0, stream>>>(spec, fn, maskb);

  // Wo conversion into region freed after spec3 (qshi/qslo dead)
  to_bf16<<<2048, 256, 0, stream>>>(Wo, wobf, HID * HID);

  // attention (bitmask-driven)
  attn_mfma<<<dim3(16, NHEADS), 256, 0, stream>>>(qbf, khi, vbf, maskb, aobf);

  // output projection
  out_gemm<<<dim3(16, 16), 512, 0, stream>>>(aobf, wobf, out);
}

// Round 6
// 258.685 us; speedup vs baseline: 7.5794x; 1.1600x over previous
//
#include <hip/hip_runtime.h>
#include <hip/hip_bf16.h>

#define S_LEN 1024
#define HID 2048
#define NHEADS 16
#define KVHEADS 4
#define HD 128
#define KVW 512
#define FETCH_MAX 204
#define ALPHA_C 5.0f
#define SCALE_C 0.08838834764831845f

typedef __attribute__((ext_vector_type(8))) short bf16x8;
typedef __attribute__((ext_vector_type(4))) float f32x4;
typedef unsigned short ushort_t;

#define MFMA16(a, b, c) __builtin_amdgcn_mfma_f32_16x16x32_bf16(a, b, c, 0, 0, 0)

__device__ __forceinline__ ushort_t f2bf(float f) {
  unsigned u = __float_as_uint(f);
  return (ushort_t)((u + 0x7fffu + ((u >> 16) & 1u)) >> 16);
}
__device__ __forceinline__ float bf2f(ushort_t h) {
  return __uint_as_float(((unsigned)h) << 16);
}

// ---------------- fp32 -> bf16, 8 elems/thread ------------------------------
__global__ __launch_bounds__(256) void to_bf16(const float* __restrict__ in,
                                               ushort_t* __restrict__ out, int n) {
  int i = (blockIdx.x * 256 + threadIdx.x) * 8;
  if (i >= n) return;
  float4 a = *(const float4*)(in + i);
  float4 b = *(const float4*)(in + i + 4);
  bf16x8 v;
  v[0] = (short)f2bf(a.x); v[1] = (short)f2bf(a.y);
  v[2] = (short)f2bf(a.z); v[3] = (short)f2bf(a.w);
  v[4] = (short)f2bf(b.x); v[5] = (short)f2bf(b.y);
  v[6] = (short)f2bf(b.z); v[7] = (short)f2bf(b.w);
  *(bf16x8*)(out + i) = v;
}

// ---------------- fp32 -> bf16 hi/lo split, 8 elems/thread ------------------
__global__ __launch_bounds__(256) void to_bf16_split(const float* __restrict__ in,
                                                     ushort_t* __restrict__ hi,
                                                     ushort_t* __restrict__ lo, int n) {
  int i = (blockIdx.x * 256 + threadIdx.x) * 8;
  if (i >= n) return;
  bf16x8 vh, vl;
#pragma unroll
  for (int q = 0; q < 8; ++q) {
    float x = in[i + q];
    ushort_t h = f2bf(x);
    vh[q] = (short)h;
    vl[q] = (short)f2bf(x - bf2f(h));
  }
  *(bf16x8*)(hi + i) = vh;
  *(bf16x8*)(lo + i) = vl;
}

// ============ ALL projections in one launch, reg-prefetch double-buffer =====
// 640 blocks x 256 thr. BM=64 BN=128 BK=64. Waves 2M x 2N; wave owns 32 rows
// x 64 cols (acc[2][4], frag cols nf = wn + 2i so RoPE pair is (i, i+2)).
// seg0: Qs 3-pass (256 blocks)  seg1: K 3-pass (64)
// seg2: Q  1-pass (256)         seg3: V 1-pass (64, no rope)
__global__ __launch_bounds__(256) void proj_all(
    const ushort_t* __restrict__ phi, const ushort_t* __restrict__ plo,
    const ushort_t* __restrict__ hhi, const ushort_t* __restrict__ hlo,
    const ushort_t* __restrict__ wqh, const ushort_t* __restrict__ wql,
    const ushort_t* __restrict__ wkh, const ushort_t* __restrict__ wkl,
    const ushort_t* __restrict__ wvh,
    ushort_t* __restrict__ oqs_h, ushort_t* __restrict__ oqs_l,
    ushort_t* __restrict__ ok_h, ushort_t* __restrict__ ok_l,
    ushort_t* __restrict__ oq, ushort_t* __restrict__ ov,
    const float* __restrict__ cosb, const float* __restrict__ sinb) {
  __shared__ char sm[49152];
  char* Ah = sm;            // 8KB
  char* Al = sm + 8192;     // 8KB
  char* Bh = sm + 16384;    // 16KB
  char* Bl = sm + 32768;    // 16KB
  const int tid = threadIdx.x, w = tid >> 6, lane = tid & 63;
  const int lo = lane & 15, hi = lane >> 4;
  const int wm = w >> 1, wn = w & 1;
  const int bid = blockIdx.x;

  int seg, idx;
  if (bid < 256)      { seg = 0; idx = bid; }
  else if (bid < 320) { seg = 1; idx = bid - 256; }
  else if (bid < 576) { seg = 2; idx = bid - 320; }
  else                { seg = 3; idx = bid - 576; }
  const int ncols = (seg == 0 || seg == 2) ? 16 : 4;
  const int bm = (idx / ncols) * 64, bn = (idx % ncols) * 128;
  const int N = ncols * 128;
  const bool three = (seg <= 1);
  const bool rope = (seg != 3);
  const ushort_t* A_h = (seg == 0) ? phi : hhi;
  const ushort_t* A_l = (seg == 0) ? plo : hlo;
  const ushort_t* W_h = (seg == 1) ? wkh : ((seg == 3) ? wvh : wqh);
  const ushort_t* W_l = (seg == 1) ? wkl : wql;

  f32x4 acc[2][4];
#pragma unroll
  for (int m = 0; m < 2; ++m)
#pragma unroll
    for (int i = 0; i < 4; ++i) acc[m][i] = f32x4{0.f, 0.f, 0.f, 0.f};

  bf16x8 rAh[2], rAl[2], rBh[4], rBl[4];

#define LOAD_TILES(K0)                                                        \
  {                                                                           \
    _Pragma("unroll")                                                         \
    for (int p = 0; p < 2; ++p) {                                             \
      int i2 = p * 256 + tid; int r = i2 >> 3, c = i2 & 7;                    \
      size_t g = (size_t)(bm + r) * HID + (K0) + c * 8;                       \
      rAh[p] = *(const bf16x8*)(A_h + g);                                     \
      if (three) rAl[p] = *(const bf16x8*)(A_l + g);                          \
    }                                                                         \
    _Pragma("unroll")                                                         \
    for (int p = 0; p < 4; ++p) {                                             \
      int i2 = p * 256 + tid; int r = i2 >> 3, c = i2 & 7;                    \
      size_t g = (size_t)(bn + r) * HID + (K0) + c * 8;                       \
      rBh[p] = *(const bf16x8*)(W_h + g);                                     \
      if (three) rBl[p] = *(const bf16x8*)(W_l + g);                          \
    }                                                                         \
  }

  LOAD_TILES(0);
  for (int k0 = 0; k0 < HID; k0 += 64) {
    // write staged regs -> LDS
#pragma unroll
    for (int p = 0; p < 2; ++p) {
      int i2 = p * 256 + tid; int r = i2 >> 3, c = i2 & 7;
      int off = (r * 128 + c * 16) ^ ((r & 7) << 4);
      *(bf16x8*)(Ah + off) = rAh[p];
      if (three) *(bf16x8*)(Al + off) = rAl[p];
    }
#pragma unroll
    for (int p = 0; p < 4; ++p) {
      int i2 = p * 256 + tid; int r = i2 >> 3, c = i2 & 7;
      int off = (r * 128 + c * 16) ^ ((r & 7) << 4);
      *(bf16x8*)(Bh + off) = rBh[p];
      if (three) *(bf16x8*)(Bl + off) = rBl[p];
    }
    __syncthreads();
    if (k0 + 64 < HID) LOAD_TILES(k0 + 64);
#pragma unroll
    for (int ks = 0; ks < 2; ++ks) {
      const int ko = ks * 64 + hi * 16;
      bf16x8 ah[2], al[2];
#pragma unroll
      for (int m = 0; m < 2; ++m) {
        int ar = wm * 32 + m * 16 + lo;
        int aoff = (ar * 128 + ko) ^ ((ar & 7) << 4);
        ah[m] = *(const bf16x8*)(Ah + aoff);
        if (three) al[m] = *(const bf16x8*)(Al + aoff);
      }
#pragma unroll
      for (int i = 0; i < 4; ++i) {
        int br = (wn + 2 * i) * 16 + lo;
        int boff = (br * 128 + ko) ^ ((br & 7) << 4);
        bf16x8 bh = *(const bf16x8*)(Bh + boff);
        if (three) {
          bf16x8 bl = *(const bf16x8*)(Bl + boff);
#pragma unroll
          for (int m = 0; m < 2; ++m) {
            acc[m][i] = MFMA16(ah[m], bh, acc[m][i]);
            acc[m][i] = MFMA16(ah[m], bl, acc[m][i]);
            acc[m][i] = MFMA16(al[m], bh, acc[m][i]);
          }
        } else {
#pragma unroll
          for (int m = 0; m < 2; ++m) acc[m][i] = MFMA16(ah[m], bh, acc[m][i]);
        }
      }
    }
    __syncthreads();
  }
#undef LOAD_TILES

  // epilogue: RoPE pairs (i, i+2): cols d and d+64 (head-local, BN==head width)
  ushort_t* Oh = (seg == 0) ? oqs_h : ok_h;
  ushort_t* Ol = (seg == 0) ? oqs_l : ok_l;
  ushort_t* O1 = (seg == 2) ? oq : ov;
#pragma unroll
  for (int m = 0; m < 2; ++m)
#pragma unroll
    for (int i = 0; i < 2; ++i)
#pragma unroll
      for (int r = 0; r < 4; ++r) {
        int t = bm + wm * 32 + m * 16 + hi * 4 + r;
        int d = (wn + 2 * i) * 16 + lo;          // < 64
        float x1 = acc[m][i][r], x2 = acc[m][i + 2][r];
        float y1, y2;
        if (rope) {
          float c1 = cosb[t * HD + d], s1 = sinb[t * HD + d];
          float c2 = cosb[t * HD + d + 64], s2 = sinb[t * HD + d + 64];
          y1 = x1 * c1 - x2 * s1;
          y2 = x2 * c2 + x1 * s2;
        } else {
          y1 = x1; y2 = x2;
        }
        size_t o1 = (size_t)t * N + bn + d;
        size_t o2 = o1 + 64;
        if (three) {
          ushort_t h1 = f2bf(y1), h2 = f2bf(y2);
          Oh[o1] = h1; Ol[o1] = f2bf(y1 - bf2f(h1));
          Oh[o2] = h2; Ol[o2] = f2bf(y2 - bf2f(h2));
        } else {
          O1[o1] = f2bf(y1);
          O1[o2] = f2bf(y2);
        }
      }
}

// ---------------- 3-pass spec GEMM, causal tiles only, reg-prefetch ---------
__global__ __launch_bounds__(256) void spec3_gemm(
    const ushort_t* __restrict__ Qhi, const ushort_t* __restrict__ Qlo,
    const ushort_t* __restrict__ Khi, const ushort_t* __restrict__ Klo,
    float* __restrict__ spec) {
  __shared__ char sm[65536];
  char* Ah = sm;
  char* Al = sm + 16384;
  char* Bh = sm + 32768;
  char* Bl = sm + 49152;
  const int tid = threadIdx.x, w = tid >> 6, lane = tid & 63;
  const int lo = lane & 15, hi = lane >> 4;
  const int bid = blockIdx.x;
  const int h = bid / 36;
  int tl = bid % 36;
  int mi = 0;
#pragma unroll
  for (int m = 1; m < 8; ++m) if ((m * (m + 1)) / 2 <= tl) mi = m;
  const int ni = tl - (mi * (mi + 1)) / 2;
  const int bm = mi * 128, bn = ni * 128;
  const ushort_t* Abh = Qhi + h * HD;
  const ushort_t* Abl = Qlo + h * HD;
  const ushort_t* Bbh = Khi + (h >> 2) * HD;
  const ushort_t* Bbl = Klo + (h >> 2) * HD;
  float* C = spec + (size_t)h * S_LEN * S_LEN;
  f32x4 acc[2][8];
#pragma unroll
  for (int m = 0; m < 2; ++m)
#pragma unroll
    for (int n = 0; n < 8; ++n) acc[m][n] = f32x4{0.f, 0.f, 0.f, 0.f};

  bf16x8 rAh[4], rAl[4], rBh[4], rBl[4];
#define LOAD_SPEC(K0)                                                         \
  {                                                                           \
    _Pragma("unroll")                                                         \
    for (int p = 0; p < 4; ++p) {                                             \
      int i2 = p * 256 + tid; int r = i2 >> 3, c = i2 & 7;                    \
      size_t ga = (size_t)(bm + r) * HID + (K0) + c * 8;                      \
      size_t gb = (size_t)(bn + r) * KVW + (K0) + c * 8;                      \
      rAh[p] = *(const bf16x8*)(Abh + ga);                                    \
      rAl[p] = *(const bf16x8*)(Abl + ga);                                    \
      rBh[p] = *(const bf16x8*)(Bbh + gb);                                    \
      rBl[p] = *(const bf16x8*)(Bbl + gb);                                    \
    }                                                                         \
  }

  LOAD_SPEC(0);
  for (int k0 = 0; k0 < HD; k0 += 64) {
#pragma unroll
    for (int p = 0; p < 4; ++p) {
      int i2 = p * 256 + tid; int r = i2 >> 3, c = i2 & 7;
      int off = (r * 128 + c * 16) ^ ((r & 7) << 4);
      *(bf16x8*)(Ah + off) = rAh[p];
      *(bf16x8*)(Al + off) = rAl[p];
      *(bf16x8*)(Bh + off) = rBh[p];
      *(bf16x8*)(Bl + off) = rBl[p];
    }
    __syncthreads();
    if (k0 + 64 < HD) LOAD_SPEC(k0 + 64);
#pragma unroll
    for (int ks = 0; ks < 2; ++ks) {
      const int ko = ks * 64 + hi * 16;
      bf16x8 ah[2], al[2];
#pragma unroll
      for (int m = 0; m < 2; ++m) {
        int r = w * 32 + m * 16 + lo;
        int off = (r * 128 + ko) ^ ((r & 7) << 4);
        ah[m] = *(const bf16x8*)(Ah + off);
        al[m] = *(const bf16x8*)(Al + off);
      }
#pragma unroll
      for (int n = 0; n < 8; ++n) {
        int r = n * 16 + lo;
        int off = (r * 128 + ko) ^ ((r & 7) << 4);
        bf16x8 bh = *(const bf16x8*)(Bh + off);
        bf16x8 bl = *(const bf16x8*)(Bl + off);
#pragma unroll
        for (int m = 0; m < 2; ++m) {
          acc[m][n] = MFMA16(ah[m], bh, acc[m][n]);
          acc[m][n] = MFMA16(ah[m], bl, acc[m][n]);
          acc[m][n] = MFMA16(al[m], bh, acc[m][n]);
        }
      }
    }
    __syncthreads();
  }
#undef LOAD_SPEC
#pragma unroll
  for (int m = 0; m < 2; ++m)
#pragma unroll
    for (int nf = 0; nf < 8; ++nf)
#pragma unroll
      for (int r = 0; r < 4; ++r) {
        int t = bm + w * 32 + m * 16 + hi * 4 + r;
        int j = bn + nf * 16 + lo;
        C[(size_t)t * S_LEN + j] = acc[m][nf][r] * SCALE_C;
      }
}

// ---------------- output GEMM: out = AO @ Wo^T, 2Mx2N waves, prefetch -------
__global__ __launch_bounds__(256) void out_gemm(
    const ushort_t* __restrict__ A, const ushort_t* __restrict__ W,
    float* __restrict__ Out) {
  __shared__ char sm[24576];
  char* As = sm;            // 8KB
  char* Bs = sm + 8192;     // 16KB
  const int tid = threadIdx.x, w = tid >> 6, lane = tid & 63;
  const int lo = lane & 15, hi = lane >> 4;
  const int wm = w >> 1, wn = w & 1;
  const int bm = blockIdx.y * 64, bn = blockIdx.x * 128;
  f32x4 acc[2][4];
#pragma unroll
  for (int m = 0; m < 2; ++m)
#pragma unroll
    for (int i = 0; i < 4; ++i) acc[m][i] = f32x4{0.f, 0.f, 0.f, 0.f};

  bf16x8 rA[2], rB[4];
#define LOAD_OUT(K0)                                                          \
  {                                                                           \
    _Pragma("unroll")                                                         \
    for (int p = 0; p < 2; ++p) {                                             \
      int i2 = p * 256 + tid; int r = i2 >> 3, c = i2 & 7;                    \
      rA[p] = *(const bf16x8*)(A + (size_t)(bm + r) * HID + (K0) + c * 8);    \
    }                                                                         \
    _Pragma("unroll")                                                         \
    for (int p = 0; p < 4; ++p) {                                             \
      int i2 = p * 256 + tid; int r = i2 >> 3, c = i2 & 7;                    \
      rB[p] = *(const bf16x8*)(W + (size_t)(bn + r) * HID + (K0) + c * 8);    \
    }                                                                         \
  }

  LOAD_OUT(0);
  for (int k0 = 0; k0 < HID; k0 += 64) {
#pragma unroll
    for (int p = 0; p < 2; ++p) {
      int i2 = p * 256 + tid; int r = i2 >> 3, c = i2 & 7;
      *(bf16x8*)(As + ((r * 128 + c * 16) ^ ((r & 7) << 4))) = rA[p];
    }
#pragma unroll
    for (int p = 0; p < 4; ++p) {
      int i2 = p * 256 + tid; int r = i2 >> 3, c = i2 & 7;
      *(bf16x8*)(Bs + ((r * 128 + c * 16) ^ ((r & 7) << 4))) = rB[p];
    }
    __syncthreads();
    if (k0 + 64 < HID) LOAD_OUT(k0 + 64);
#pragma unroll
    for (int ks = 0; ks < 2; ++ks) {
      const int ko = ks * 64 + hi * 16;
      bf16x8 ah[2];
#pragma unroll
      for (int m = 0; m < 2; ++m) {
        int ar = wm * 32 + m * 16 + lo;
        ah[m] = *(const bf16x8*)(As + ((ar * 128 + ko) ^ ((ar & 7) << 4)));
      }
#pragma unroll
      for (int i = 0; i < 4; ++i) {
        int br = (wn + 2 * i) * 16 + lo;
        bf16x8 bf = *(const bf16x8*)(Bs + ((br * 128 + ko) ^ ((br & 7) << 4)));
#pragma unroll
        for (int m = 0; m < 2; ++m) acc[m][i] = MFMA16(ah[m], bf, acc[m][i]);
      }
    }
    __syncthreads();
  }
#undef LOAD_OUT
#pragma unroll
  for (int m = 0; m < 2; ++m)
#pragma unroll
    for (int i = 0; i < 4; ++i)
#pragma unroll
      for (int r = 0; r < 4; ++r) {
        int t = bm + wm * 32 + m * 16 + hi * 4 + r;
        Out[(size_t)t * HID + bn + (wn + 2 * i) * 16 + lo] = acc[m][i][r];
      }
}

// ---------------- per-(h,t>=204): rowmax + count(>= max-ALPHA), LDS-cached --
__global__ __launch_bounds__(256) void count_kernel(
    const float* __restrict__ spec, int* __restrict__ cnt) {
  const int t = blockIdx.x + FETCH_MAX, h = blockIdx.y, tid = threadIdx.x;
  const int w = tid >> 6, lane = tid & 63;
  __shared__ float rowc[1024];
  __shared__ float wmax[4];
  __shared__ int wcnt[4];
  const float* row = spec + ((size_t)h * S_LEN + t) * S_LEN;
  float mx = -1e30f;
  for (int j = tid; j <= t; j += 256) {
    float v = row[j];
    rowc[j] = v;
    mx = fmaxf(mx, v);
  }
#pragma unroll
  for (int d = 1; d < 64; d <<= 1) mx = fmaxf(mx, __shfl_xor(mx, d));
  if (lane == 0) wmax[w] = mx;
  __syncthreads();
  const float cut = fmaxf(fmaxf(wmax[0], wmax[1]), fmaxf(wmax[2], wmax[3])) - ALPHA_C;
  int c = 0;
  for (int j = tid; j <= t; j += 256) c += (rowc[j] >= cut) ? 1 : 0;
#pragma unroll
  for (int d = 1; d < 64; d <<= 1) c += __shfl_xor(c, d);
  if (lane == 0) wcnt[w] = c;
  __syncthreads();
  if (tid == 0) cnt[h * S_LEN + t] = wcnt[0] + wcnt[1] + wcnt[2] + wcnt[3];
}

__global__ __launch_bounds__(256) void fn_kernel(
    const int* __restrict__ cnt, int* __restrict__ fn) {
  int t = FETCH_MAX + blockIdx.x * 256 + threadIdx.x;
  if (t >= S_LEN) return;
  int s = 0;
#pragma unroll
  for (int h = 0; h < NHEADS; ++h) s += cnt[h * S_LEN + t];
  int f = s >> 4;
  fn[t] = f > FETCH_MAX ? FETCH_MAX : f;
}

// ---- wave-0 parallel bin select: largest bin b with suffix-count >= k ------
__device__ __forceinline__ void select_bin(const int* hist, int k, int w, int lane,
                                           int* sh_bin, int* sh_k) {
  if (w == 0) {
    const int base = 252 - 4 * lane;
    int c0 = hist[base], c1 = hist[base + 1], c2 = hist[base + 2], c3 = hist[base + 3];
    int s = c0 + c1 + c2 + c3;
    int p = s;
#pragma unroll
    for (int d = 1; d < 64; d <<= 1) {
      int q = __shfl_up(p, d);
      if (lane >= d) p += q;
    }
    unsigned long long m = __ballot(p >= k);
    int lsel = __ffsll((unsigned long long)m) - 1;
    if (lane == lsel) {
      int cum = p - s;
      int b;
      if (cum + c3 >= k) { b = base + 3; }
      else if (cum + c3 + c2 >= k) { cum += c3; b = base + 2; }
      else if (cum + c3 + c2 + c1 >= k) { cum += c3 + c2; b = base + 1; }
      else { cum += c3 + c2 + c1; b = base; }
      *sh_bin = b;
      *sh_k = k - cum;
    }
  }
}

// ---------------- exact k-th largest -> bitmask, LDS-cached radix select ----
__global__ __launch_bounds__(256) void thr_kernel(
    const float* __restrict__ spec, const int* __restrict__ fn,
    unsigned long long* __restrict__ maskb) {
  const int t = blockIdx.x + FETCH_MAX, h = blockIdx.y;
  const int tid = threadIdx.x, w = tid >> 6, lane = tid & 63;
  __shared__ unsigned rowk[1024];
  __shared__ unsigned candA[1024];
  __shared__ unsigned candB[1024];
  __shared__ int hist4[4][256];
  __shared__ int hist[256];
  __shared__ int sh_bin, sh_k, sh_cnt;
  const float* row = spec + ((size_t)h * S_LEN + t) * S_LEN;
  const int n0 = t + 1;
  int k = fn[t];
  hist4[0][tid] = 0; hist4[1][tid] = 0; hist4[2][tid] = 0; hist4[3][tid] = 0;
  if (tid == 0) sh_cnt = 0;
  __syncthreads();
  for (int j = tid; j < n0; j += 256) {
    unsigned bits = __float_as_uint(row[j]);
    unsigned u = (bits & 0x80000000u) ? ~bits : (bits | 0x80000000u);
    rowk[j] = u;
    atomicAdd(&hist4[w][u >> 24], 1);
  }
  __syncthreads();
  hist[tid] = hist4[0][tid] + hist4[1][tid] + hist4[2][tid] + hist4[3][tid];
  __syncthreads();
  select_bin(hist, k, w, lane, &sh_bin, &sh_k);
  __syncthreads();
  unsigned prefix = (unsigned)sh_bin << 24;
  k = sh_k;
  {
    const unsigned bsel = (unsigned)sh_bin;
    for (int j = tid; j < n0; j += 256) {
      unsigned u = rowk[j];
      if ((u >> 24) == bsel) candA[atomicAdd(&sh_cnt, 1)] = u;
    }
  }
  __syncthreads();
  int n = sh_cnt;
  unsigned* src = candA;
  unsigned* dst = candB;
#pragma unroll
  for (int rd = 0; rd < 3; ++rd) {
    const int shift = 16 - rd * 8;
    hist[tid] = 0;
    __syncthreads();
    for (int j = tid; j < n; j += 256) atomicAdd(&hist[(src[j] >> shift) & 255u], 1);
    __syncthreads();
    select_bin(hist, k, w, lane, &sh_bin, &sh_k);
    if (tid == 1) sh_cnt = 0;
    __syncthreads();
    const unsigned bsel = (unsigned)sh_bin;
    prefix |= bsel << shift;
    k = sh_k;
    if (shift > 0) {
      for (int j = tid; j < n; j += 256) {
        unsigned u = src[j];
        if (((u >> shift) & 255u) == bsel) dst[atomicAdd(&sh_cnt, 1)] = u;
      }
      __syncthreads();
      n = sh_cnt;
      unsigned* tmp = src; src = dst; dst = tmp;
    }
  }
  const unsigned kth = prefix;
#pragma unroll
  for (int s4 = 0; s4 < 4; ++s4) {
    int j = s4 * 256 + w * 64 + lane;
    bool bit = (j < n0) && (rowk[j] >= kth);
    unsigned long long m = __ballot(bit);
    if (lane == 0) maskb[((size_t)h * S_LEN + t) * 16 + (s4 * 4 + w)] = m;
  }
}

// ---------------- flash-style MFMA attention with bitmask -------------------
__global__ __launch_bounds__(256) void attn_mfma(
    const ushort_t* __restrict__ Qbf, const ushort_t* __restrict__ Kbf,
    const ushort_t* __restrict__ Vbf, const unsigned long long* __restrict__ maskb,
    ushort_t* __restrict__ AO) {
  __shared__ char sm[41984];
  const int tid = threadIdx.x, w = tid >> 6, lane = tid & 63;
  const int lo = lane & 15, hi = lane >> 4;
  const int rt = blockIdx.x, h = blockIdx.y;
  const int kvh = h >> 2;
  const int qrow = rt * 64 + w * 16 + lo;
  const int t0 = rt * 64 + w * 16 + hi * 4;

  bf16x8 qf[4];
  const ushort_t* qp = Qbf + (size_t)qrow * HID + h * HD;
#pragma unroll
  for (int ks = 0; ks < 4; ++ks) qf[ks] = *(const bf16x8*)(qp + ks * 32 + hi * 8);

  float mrun[4], lrun[4];
  f32x4 o[8];
#pragma unroll
  for (int r = 0; r < 4; ++r) { mrun[r] = -1e30f; lrun[r] = 0.f; }
#pragma unroll
  for (int n = 0; n < 8; ++n) o[n] = f32x4{0.f, 0.f, 0.f, 0.f};

  const int ntiles = rt + 1;
  for (int jt = 0; jt < ntiles; ++jt) {
    const int j0 = jt * 64;
#pragma unroll
    for (int p = 0; p < 4; ++p) {
      int idx = p * 256 + tid;
      int r = idx >> 4, c = idx & 15;
      bf16x8 v = *(const bf16x8*)(Kbf + (size_t)(j0 + r) * KVW + kvh * HD + c * 8);
      *(bf16x8*)(sm + ((r * 256 + c * 16) ^ ((r & 7) << 4))) = v;
    }
#pragma unroll
    for (int p = 0; p < 4; ++p) {
      int idx = p * 256 + tid;
      int j = idx & 63, dc = idx >> 6;
      bf16x8 v = *(const bf16x8*)(Vbf + (size_t)(j0 + j) * KVW + kvh * HD + dc * 8);
#pragma unroll
      for (int i = 0; i < 8; ++i) {
        int d = dc * 8 + i;
        *(ushort_t*)(sm + 16384 + ((d * 128 + j * 2) ^ ((d & 7) << 4))) = (ushort_t)v[i];
      }
    }
    __syncthreads();
    f32x4 s[4];
#pragma unroll
    for (int nf = 0; nf < 4; ++nf) {
      f32x4 a = f32x4{0.f, 0.f, 0.f, 0.f};
#pragma unroll
      for (int ks = 0; ks < 4; ++ks) {
        int r = nf * 16 + lo;
        bf16x8 kfr = *(const bf16x8*)(sm + ((r * 256 + ks * 64 + hi * 16) ^ ((r & 7) << 4)));
        a = MFMA16(qf[ks], kfr, a);
      }
      s[nf] = a;
    }
    unsigned long long wbits[4];
#pragma unroll
    for (int r = 0; r < 4; ++r) {
      int t = t0 + r;
      wbits[r] = (t >= FETCH_MAX) ? maskb[((size_t)h * S_LEN + t) * 16 + jt] : ~0ull;
    }
    float pvv[4][4];
    float tmax[4] = {-1e30f, -1e30f, -1e30f, -1e30f};
#pragma unroll
    for (int nf = 0; nf < 4; ++nf) {
      int j = j0 + nf * 16 + lo;
#pragma unroll
      for (int r = 0; r < 4; ++r) {
        int t = t0 + r;
        bool ok = (j <= t) && ((wbits[r] >> (nf * 16 + lo)) & 1ull);
        float val = ok ? s[nf][r] * SCALE_C : -1e30f;
        pvv[nf][r] = val;
        tmax[r] = fmaxf(tmax[r], val);
      }
    }
#pragma unroll
    for (int r = 0; r < 4; ++r) {
      float m = tmax[r];
      m = fmaxf(m, __shfl_xor(m, 1));
      m = fmaxf(m, __shfl_xor(m, 2));
      m = fmaxf(m, __shfl_xor(m, 4));
      m = fmaxf(m, __shfl_xor(m, 8));
      tmax[r] = m;
    }
    float alpha[4];
#pragma unroll
    for (int r = 0; r < 4; ++r) {
      float mnew = fmaxf(mrun[r], tmax[r]);
      alpha[r] = __expf(mrun[r] - mnew);
      mrun[r] = mnew;
    }
    float lsum[4] = {0.f, 0.f, 0.f, 0.f};
#pragma unroll
    for (int nf = 0; nf < 4; ++nf)
#pragma unroll
      for (int r = 0; r < 4; ++r) {
        float v2 = pvv[nf][r];
        float p = (v2 > -1e29f) ? __expf(v2 - mrun[r]) : 0.f;
        pvv[nf][r] = p;
        lsum[r] += p;
      }
#pragma unroll
    for (int r = 0; r < 4; ++r) {
      float ls = lsum[r];
      ls += __shfl_xor(ls, 1);
      ls += __shfl_xor(ls, 2);
      ls += __shfl_xor(ls, 4);
      ls += __shfl_xor(ls, 8);
      lrun[r] = lrun[r] * alpha[r] + ls;
#pragma unroll
      for (int n = 0; n < 8; ++n) o[n][r] *= alpha[r];
    }
    char* pb = sm + 32768 + w * 2304;
#pragma unroll
    for (int nf = 0; nf < 4; ++nf)
#pragma unroll
      for (int r = 0; r < 4; ++r)
        *(ushort_t*)(pb + (hi * 4 + r) * 144 + (nf * 16 + lo) * 2) = f2bf(pvv[nf][r]);
#pragma unroll
    for (int ks = 0; ks < 2; ++ks) {
      bf16x8 pa = *(const bf16x8*)(pb + lo * 144 + ks * 64 + hi * 16);
#pragma unroll
      for (int df = 0; df < 8; ++df) {
        int d = df * 16 + lo;
        bf16x8 vb = *(const bf16x8*)(sm + 16384 + ((d * 128 + ks * 64 + hi * 16) ^ ((d & 7) << 4)));
        o[df] = MFMA16(pa, vb, o[df]);
      }
    }
    __syncthreads();
  }
#pragma unroll
  for (int r = 0; r < 4; ++r) {
    float inv = 1.0f / lrun[r];
    int t = t0 + r;
#pragma unroll
    for (int df = 0; df < 8; ++df)
      AO[(size_t)t * HID + h * HD + df * 16 + lo] = f2bf(o[df][r] * inv);
  }
}

extern "C" void kernel_launch(void* const* d_in, const int* in_sizes, int n_in,
                              void* d_out, int out_size, void* d_ws, size_t ws_size,
                              hipStream_t stream) {
  const float* hidden = (const float*)d_in[0];
  const float* prev   = (const float*)d_in[1];
  const float* cosb   = (const float*)d_in[2];
  const float* sinb   = (const float*)d_in[3];
  const float* Wq     = (const float*)d_in[4];
  const float* Wk     = (const float*)d_in[5];
  const float* Wv     = (const float*)d_in[6];
  const float* Wo     = (const float*)d_in[7];
  float* out = (float*)d_out;

  char* ws = (char*)d_ws;
  const size_t MB = 1u << 20;
  float*    spec = (float*)(ws + 0);
  ushort_t* phi  = (ushort_t*)(ws + 0);
  ushort_t* plo  = (ushort_t*)(ws + 4 * MB);
  ushort_t* wqhi = (ushort_t*)(ws + 8 * MB);
  ushort_t* wqlo = (ushort_t*)(ws + 16 * MB);
  ushort_t* wkhi = (ushort_t*)(ws + 24 * MB);
  ushort_t* wklo = (ushort_t*)(ws + 26 * MB);
  ushort_t* hhi  = (ushort_t*)(ws + 64 * MB);
  ushort_t* hlo  = (ushort_t*)(ws + 68 * MB);
  ushort_t* qbf  = (ushort_t*)(ws + 72 * MB);
  ushort_t* qshi = (ushort_t*)(ws + 76 * MB);
  ushort_t* qslo = (ushort_t*)(ws + 80 * MB);
  ushort_t* khi  = (ushort_t*)(ws + 84 * MB);
  ushort_t* klo  = (ushort_t*)(ws + 85 * MB);
  ushort_t* vbf  = (ushort_t*)(ws + 86 * MB);
  ushort_t* wvbf = (ushort_t*)(ws + 87 * MB);
  int*   cnt = (int*)  (ws + 89 * MB);
  int*   fn  = (int*)  (ws + 89 * MB + (64u << 10));
  unsigned long long* maskb = (unsigned long long*)(ws + 90 * MB);  // 2MB
  ushort_t* wobf = (ushort_t*)(ws + 76 * MB);
  ushort_t* aobf = (ushort_t*)(ws + 64 * MB);

  // conversions
  to_bf16_split<<<1024, 256, 0, stream>>>(hidden, hhi, hlo, S_LEN * HID);
  to_bf16_split<<<1024, 256, 0, stream>>>(prev, phi, plo, S_LEN * HID);
  to_bf16_split<<<2048, 256, 0, stream>>>(Wq, wqhi, wqlo, HID * HID);
  to_bf16_split<<<512, 256, 0, stream>>>(Wk, wkhi, wklo, KVW * HID);
  to_bf16<<<512, 256, 0, stream>>>(Wv, wvbf, KVW * HID);

  // all projections in one launch
  proj_all<<<640, 256, 0, stream>>>(phi, plo, hhi, hlo, wqhi, wqlo, wkhi, wklo,
                                    wvbf, qshi, qslo, khi, klo, qbf, vbf,
                                    cosb, sinb);

  // speculative scores (fp32-accurate, causal tiles only)
  spec3_gemm<<<576, 256, 0, stream>>>(qshi, qslo, khi, klo, spec);

  // mask statistics (exact on fp32 spec)
  count_kernel<<<dim3(S_LEN - FETCH_MAX, NHEADS), 256, 0, stream>>>(spec, cnt);
  fn_kernel<<<(S_LEN - FETCH_MAX + 255) / 256, 256, 0, stream>>>(cnt, fn);
  thr_kernel<<<dim3(S_LEN - FETCH_MAX, NHEADS), 256, 0, stream>>>(spec, fn, maskb);

  // Wo conversion into region freed after spec3 (qshi/qslo dead)
  to_bf16<<<2048, 256, 0, stream>>>(Wo, wobf, HID * HID);

  // attention (bitmask-driven)
  attn_mfma<<<dim3(16, NHEADS), 256, 0, stream>>>(qbf, khi, vbf, maskb, aobf);

  // output projection
  out_gemm<<<dim3(16, 16), 256, 0, stream>>>(aobf, wobf, out);
}